// Round 12
// baseline (312.516 us; speedup 1.0000x reference)
//
#include <hip/hip_runtime.h>

#define NB 16
#define QL 512
#define KL 1024
#define DM 384
#define NH 3
#define DK 128

typedef unsigned short u16;
typedef __attribute__((ext_vector_type(8))) short bf16x8;
typedef __attribute__((ext_vector_type(4))) float f32x4;
typedef __attribute__((ext_vector_type(4))) unsigned int u32x4;

// ---------------- workspace byte offsets ----------------
static const size_t B_W2Q = 0;            // bf16 [384][1664] (granule-swizzled)
static const size_t B_W2K = 1277952;
static const size_t B_W2V = 2555904;
static const size_t B_WLB = 3833856;      // bf16 [384][384]
static const size_t B_QH  = 4128768;      // bf16 [16*512][384]
static const size_t B_KH  = 10420224;     // bf16 [16*1024][384]
static const size_t B_VH  = 23003136;     // bf16 [16*1024][384]
static const size_t B_E   = 67043328;     // bf16 [48][512][1024]
static const size_t B_AMT = 100597760;    // bf16 [16][512][1024] (aliases dead E-high)
static const size_t B_MS  = 117374976;    // f32 [48*512][2] {rowmax, inv}
static const size_t B_CPART = 117571584;  // f32 [48][8][1024]
static const size_t B_FRR = 119144448;    // f32 [48]
static const size_t B_HIDX = 119144704;   // int [16]
static const size_t B_PT  = 119144960;    // f32 [16][1024][512] (+64KB slack after)
static const size_t B_VHT = 152764928;    // bf16 [16][384][1024]
static const size_t B_CVP = 165347840;    // bf16 [16][512][384]

// d_out offsets (floats)
static const size_t OUT_CV    = 0;
static const size_t OUT_ALPHA = 3145728;
static const size_t OUT_FR    = 11534336;

__device__ __forceinline__ u16 f2b(float x) {
  union { float f; unsigned u; } q; q.f = x;
  unsigned r = q.u + 0x7fffu + ((q.u >> 16) & 1u);
  return (u16)(r >> 16);
}
__device__ __forceinline__ float b2f(u16 h) {
  union { unsigned u; float f; } q; q.u = ((unsigned)h) << 16;
  return q.f;
}

typedef __attribute__((address_space(3))) void lds_void;
typedef __attribute__((address_space(1))) const void g_void;
__device__ __forceinline__ void gload_lds16(const void* g, void* l) {
  __builtin_amdgcn_global_load_lds((g_void*)g, (lds_void*)l, 16, 0, 0);
}

// ---------------- weight repacks ----------------
__global__ __launch_bounds__(256) void repack_all(
    const float* __restrict__ wq, const float* __restrict__ wk,
    const float* __restrict__ wv, const float* __restrict__ wl,
    u16* __restrict__ dq, u16* __restrict__ dk, u16* __restrict__ dv,
    u16* __restrict__ dl) {
  const int z = blockIdx.z;
  const int tid = blockIdx.x * 256 + threadIdx.x;
  if (z < 3) {
    if (tid >= 384 * 1664) return;
    const float* src = (z == 0) ? wq : (z == 1) ? wk : wv;
    u16* dst = (z == 0) ? dq : (z == 1) ? dk : dv;
    const int oc = tid / 1664, k = tid % 1664;     // logical k
    const int t = k >> 7, ic = k & 127;
    const int g = (k >> 3) & 7, e = k & 7;
    const int pcol = (k & ~63) + (((g ^ (oc & 7))) << 3) + e;
    dst[(size_t)oc * 1664 + pcol] = f2b(src[(size_t)oc * 1664 + ic * 13 + t]);
  } else {
    if (tid < 384 * 384) dl[tid] = f2b(wl[tid]);
  }
}

// ---------------- grouped conv1d: 2-pass ic-split; double-buffered Bs, 1 barrier/K-step ----
// z/3 selects tensor (0=q L=512, 1=k, 2=v L=1024); z%3 = group
__global__ __launch_bounds__(256, 3) void conv_mfma(
    const float* __restrict__ xq, const float* __restrict__ xk, const float* __restrict__ xv,
    const u16* __restrict__ wq, const u16* __restrict__ wk, const u16* __restrict__ wv,
    const float* __restrict__ bq, const float* __restrict__ bk, const float* __restrict__ bv,
    u16* __restrict__ oq, u16* __restrict__ ok, u16* __restrict__ ov)
{
  __shared__ __align__(16) u16 xw[140][72];
  __shared__ __align__(16) u16 Bs[2][128 * 64];   // unpadded, granule-swizzled content
  const int z = blockIdx.z;
  const int which = z / 3, g = z % 3;
  const float* X; const u16* W; const float* bias; u16* out; int Lmask;
  if (which == 0)      { X = xq; W = wq; bias = bq; out = oq; Lmask = 511; }
  else if (which == 1) { X = xk; W = wk; bias = bk; out = ok; Lmask = 1023; }
  else                 { X = xv; W = wv; bias = bv; out = ov; Lmask = 1023; }
  const int m0 = blockIdx.x * 128;
  if (m0 >= NB * (Lmask + 1)) return;
  X += g * DK; W += (size_t)g * DK * 1664; bias += g * DK; out += g * DK;

  const int tid = threadIdx.x;
  const int l0 = m0 & Lmask, bbase = m0 & ~Lmask;

  const int wv_ = tid >> 6, lane = tid & 63;
  const int wr = (wv_ >> 1) * 64, wc = (wv_ & 1) * 64;
  const int fr = lane & 15, fk8 = (lane >> 4);
  const int srow = lane >> 3, sg = lane & 7;

  f32x4 acc[4][4];
  const f32x4 zero4 = {0.f, 0.f, 0.f, 0.f};
  #pragma unroll
  for (int m = 0; m < 4; ++m)
    #pragma unroll
    for (int n = 0; n < 4; ++n) acc[m][n] = zero4;

  int s = 0;
  for (int h = 0; h < 2; ++h) {
    __syncthreads();   // all reads of xw (prev pass) done
    // stage this pass's 140-row x 64-ic window, f32 -> bf16 in flight
    for (int i = tid; i < 140 * 16; i += 256) {
      const int r = i >> 4, c4 = (i & 15) * 4;
      const int l = l0 - 6 + r;
      float4 v = make_float4(0.f, 0.f, 0.f, 0.f);
      if ((unsigned)l <= (unsigned)Lmask)
        v = *(const float4*)&X[(size_t)(bbase + l) * DM + h * 64 + c4];
      union { u16 u[4]; uint2 d; } o;
      o.u[0] = f2b(v.x); o.u[1] = f2b(v.y); o.u[2] = f2b(v.z); o.u[3] = f2b(v.w);
      *(uint2*)&xw[r][c4] = o.d;
    }
    // issue t=0 weight loads into Bs[s&1]
    {
      const int k0 = h * 64;
      #pragma unroll
      for (int i = 0; i < 4; ++i) {
        const int ii = wv_ + i * 4;
        gload_lds16(&W[(size_t)(8 * ii + srow) * 1664 + k0 + sg * 8],
                    (char*)Bs[s & 1] + ii * 1024);
      }
    }
    for (int t = 0; t < 13; ++t) {
      __syncthreads();   // drains vmcnt+lgkm: xw staging + Bs[s&1] loads ready
      if (t < 12) {
        const int k0n = (t + 1) * 128 + h * 64;
        #pragma unroll
        for (int i = 0; i < 4; ++i) {
          const int ii = wv_ + i * 4;
          gload_lds16(&W[(size_t)(8 * ii + srow) * 1664 + k0n + sg * 8],
                      (char*)Bs[(s + 1) & 1] + ii * 1024);
        }
      }
      const u16* Bcur = Bs[s & 1];
      #pragma unroll
      for (int ks = 0; ks < 2; ++ks) {
        bf16x8 av[4], bv_[4];
        #pragma unroll
        for (int m = 0; m < 4; ++m)
          av[m] = *(const bf16x8*)&xw[t + wr + m * 16 + fr][ks * 32 + fk8 * 8];
        #pragma unroll
        for (int n = 0; n < 4; ++n) {
          const int r = wc + n * 16 + fr;
          const int pg = (ks * 4 + fk8) ^ (fr & 7);
          bv_[n] = *(const bf16x8*)&Bcur[r * 64 + pg * 8];
        }
        #pragma unroll
        for (int m = 0; m < 4; ++m)
          #pragma unroll
          for (int n = 0; n < 4; ++n)
            acc[m][n] = __builtin_amdgcn_mfma_f32_16x16x32_bf16(av[m], bv_[n], acc[m][n], 0, 0, 0);
      }
      ++s;
    }
  }

  const int crow = (lane >> 4) * 4;
  #pragma unroll
  for (int m = 0; m < 4; ++m) {
    #pragma unroll
    for (int n = 0; n < 4; ++n) {
      const int gm = m0 + wr + m * 16 + crow;
      const int gn = wc + n * 16 + fr;
      const float bval = bias[gn];
      #pragma unroll
      for (int j = 0; j < 4; ++j)
        out[(size_t)(gm + j) * DM + gn] = f2b(acc[m][n][j] + bval);
    }
  }
}

// ---------------- qk: E[z][q][k] = qh.kh/sqrt(128) (bf16 out) + fused row-max ----------------
__global__ __launch_bounds__(256) void qk_flash(
    const u16* __restrict__ QH, const u16* __restrict__ KH,
    u16* __restrict__ E, float* __restrict__ MS)
{
  __shared__ __align__(16) u16 As[128][136];
  __shared__ __align__(16) u16 Bs[128][136];
  __shared__ float rmx[2][128];
  const int tid = threadIdx.x;
  const int z = blockIdx.z, h = z >> 4, b = z & 15;
  const int m0 = blockIdx.x * 128;
  const u16* Ag = QH + ((size_t)b * QL + m0) * DM + h * DK;
  const u16* Bg = KH + (size_t)b * KL * DM + h * DK;
  u16* Ez = E + (size_t)z * QL * KL;

  for (int i = tid; i < 128 * 16; i += 256) {
    const int r = i >> 4, s = i & 15;
    *(uint4*)&As[r][s * 8] = *(const uint4*)&Ag[(size_t)r * DM + s * 8];
  }

  const int wv_ = tid >> 6, lane = tid & 63;
  const int wr = (wv_ >> 1) * 64, wc = (wv_ & 1) * 64;
  const int fr = lane & 15, fk = (lane >> 4) * 8;
  const int crow = (lane >> 4) * 4;
  const float sc = 0.08838834764831845f;

  float mx[4][4];
  #pragma unroll
  for (int m = 0; m < 4; ++m)
    #pragma unroll
    for (int j = 0; j < 4; ++j) mx[m][j] = -1e30f;

  for (int nt = 0; nt < 8; ++nt) {
    if (nt) __syncthreads();
    for (int i = tid; i < 128 * 16; i += 256) {
      const int r = i >> 4, s = i & 15;
      *(uint4*)&Bs[r][s * 8] = *(const uint4*)&Bg[(size_t)(nt * 128 + r) * DM + s * 8];
    }
    __syncthreads();

    f32x4 acc[4][4];
    const f32x4 zero4 = {0.f, 0.f, 0.f, 0.f};
    #pragma unroll
    for (int m = 0; m < 4; ++m)
      #pragma unroll
      for (int n = 0; n < 4; ++n) acc[m][n] = zero4;
    #pragma unroll
    for (int ks = 0; ks < 4; ++ks) {
      bf16x8 av[4], bv_[4];
      #pragma unroll
      for (int m = 0; m < 4; ++m)
        av[m] = *(const bf16x8*)&As[wr + m * 16 + fr][ks * 32 + fk];
      #pragma unroll
      for (int n = 0; n < 4; ++n)
        bv_[n] = *(const bf16x8*)&Bs[wc + n * 16 + fr][ks * 32 + fk];
      #pragma unroll
      for (int m = 0; m < 4; ++m)
        #pragma unroll
        for (int n = 0; n < 4; ++n)
          acc[m][n] = __builtin_amdgcn_mfma_f32_16x16x32_bf16(av[m], bv_[n], acc[m][n], 0, 0, 0);
    }
    #pragma unroll
    for (int m = 0; m < 4; ++m) {
      #pragma unroll
      for (int n = 0; n < 4; ++n) {
        const int gm = m0 + wr + m * 16 + crow;
        const int gn = nt * 128 + wc + n * 16 + fr;
        #pragma unroll
        for (int j = 0; j < 4; ++j) {
          const float vv = acc[m][n][j] * sc;
          mx[m][j] = fmaxf(mx[m][j], vv);
          Ez[(size_t)(gm + j) * KL + gn] = f2b(vv);
        }
      }
    }
  }

  #pragma unroll
  for (int m = 0; m < 4; ++m)
    #pragma unroll
    for (int j = 0; j < 4; ++j) {
      #pragma unroll
      for (int off = 1; off < 16; off <<= 1)
        mx[m][j] = fmaxf(mx[m][j], __shfl_xor(mx[m][j], off));
    }
  if ((lane & 15) == 0) {
    #pragma unroll
    for (int m = 0; m < 4; ++m)
      #pragma unroll
      for (int j = 0; j < 4; ++j)
        rmx[wv_ & 1][wr + m * 16 + crow + j] = mx[m][j];
  }
  __syncthreads();
  if (tid < 128)
    MS[2 * ((size_t)z * QL + m0 + tid)] = fmaxf(rmx[0][tid], rmx[1][tid]);
}

// ---------------- per (z,qc): softmax denominators + column-max partials ----------
__global__ __launch_bounds__(1024) void colsum_colmax(
    const u16* __restrict__ E, float* __restrict__ MS, float* __restrict__ cpart)
{
  const int z = blockIdx.x, qc = blockIdx.y, kk = threadIdx.x;
  __shared__ float mq[64], wsum[64][17], invs[64];
  if (kk < 64) mq[kk] = MS[2 * ((size_t)z * QL + qc * 64 + kk)];
  __syncthreads();
  const u16* base = E + ((size_t)z * QL + qc * 64) * KL + kk;
  float ex[64];
  #pragma unroll
  for (int qq = 0; qq < 64; ++qq)
    ex[qq] = expf(b2f(base[(size_t)qq * KL]) - mq[qq]);
  const int wid = kk >> 6, lane = kk & 63;
  #pragma unroll
  for (int qq = 0; qq < 64; ++qq) {
    float s = ex[qq];
    #pragma unroll
    for (int off = 1; off < 64; off <<= 1) s += __shfl_xor(s, off);
    if (lane == 0) wsum[qq][wid] = s;
  }
  __syncthreads();
  if (kk < 64) {
    float s = 0.f;
    #pragma unroll
    for (int w = 0; w < 16; ++w) s += wsum[kk][w];
    const float inv = 1.f / s;
    invs[kk] = inv;
    MS[2 * ((size_t)z * QL + qc * 64 + kk) + 1] = inv;
  }
  __syncthreads();
  float cm = 0.f;
  #pragma unroll
  for (int qq = 0; qq < 64; ++qq) cm = fmaxf(cm, ex[qq] * invs[qq]);
  cpart[((size_t)z * 8 + qc) * KL + kk] = cm;
}

// ---------------- fr per (h,b): sum_k max over 8 q-chunks ----------------
__global__ __launch_bounds__(256) void head_fr(const float* __restrict__ cpart,
                                               float* __restrict__ frr) {
  const int z = blockIdx.x, tid = threadIdx.x;
  float s = 0.f;
  for (int k = tid; k < KL; k += 256) {
    float m = 0.f;
    #pragma unroll
    for (int c = 0; c < 8; ++c) m = fmaxf(m, cpart[((size_t)z * 8 + c) * KL + k]);
    s += m;
  }
  #pragma unroll
  for (int off = 32; off; off >>= 1) s += __shfl_xor(s, off);
  __shared__ float red[4];
  if ((tid & 63) == 0) red[tid >> 6] = s;
  __syncthreads();
  if (tid == 0) frr[z] = red[0] + red[1] + red[2] + red[3];
}

// ---------------- head select ----------------
__global__ void select_head(const float* __restrict__ frr, const int* __restrict__ mel,
                            int* __restrict__ hidx, float* __restrict__ fr_out) {
  __shared__ float bf[16];
  const int b = threadIdx.x;
  if (b < 16) {
    float best = -1e30f; int bh = 0;
    for (int h = 0; h < NH; ++h) {
      float fr = frr[h * 16 + b] / (float)mel[b];
      if (fr > best) { best = fr; bh = h; }
    }
    hidx[b] = bh;
    bf[b] = best;
  }
  __syncthreads();
  if (threadIdx.x == 0) {
    float s = 0.f;
    for (int i = 0; i < 16; ++i) s += bf[i];
    *fr_out = s / 16.f;
  }
}

// ---------------- gather selected head: alpha -> d_out; sigmoid(alpha)^T -> pT ----------------
__global__ __launch_bounds__(256) void gather_fused(
    const u16* __restrict__ E, const float* __restrict__ ms,
    const int* __restrict__ hidx, float* __restrict__ afc, float* __restrict__ pT)
{
  __shared__ float tile[32][33];
  const int b = blockIdx.z, k0 = blockIdx.x * 32, q0 = blockIdx.y * 32;
  const int hb = hidx[b];
  const u16* src = E + (size_t)(hb * 16 + b) * QL * KL;
  const float* msb = ms + 2 * ((size_t)(hb * 16 + b) * QL + q0);
  const int tx = threadIdx.x, ty = threadIdx.y;
  #pragma unroll
  for (int yy = 0; yy < 4; ++yy) {
    int r = ty + 8 * yy;
    float m = msb[2 * r], inv = msb[2 * r + 1];
    float v = expf(b2f(src[(size_t)(q0 + r) * KL + k0 + tx]) - m) * inv;
    afc[((size_t)b * QL + q0 + r) * KL + k0 + tx] = v;
    tile[r][tx] = v;
  }
  __syncthreads();
  #pragma unroll
  for (int yy = 0; yy < 4; ++yy) {
    int c = ty + 8 * yy;
    float v = tile[tx][c];
    pT[((size_t)b * KL + k0 + c) * QL + q0 + tx] = 1.f / (1.f + expf(-v));
  }
}

// ================= scan: asm prefetch + counted vmcnt + in-register transpose to bf16 ======
// (round-8 proven form, verbatim)
#define ALOAD(dst, base, OFF) \
  asm volatile("global_load_dwordx4 %0, %1, off offset:" OFF : "=v"(dst) : "v"(base))
#define ASTORE16(base, OFF, val) \
  asm volatile("global_store_dwordx4 %0, %1, off offset:" OFF :: "v"(base), "v"(val) : "memory")
#define WAITVM(N) do { \
  asm volatile("s_waitcnt vmcnt(" N ")" ::: "memory"); \
  __builtin_amdgcn_sched_barrier(0); } while (0)
#define CVTPK(d, lo, hi) \
  asm("v_cvt_pk_bf16_f32 %0, %1, %2" : "=v"(d) : "v"(lo), "v"(hi))

// load 8 rows (16 dwordx4) starting at LD into BUF[8][2]
#define LOAD_CHUNK(BUF, LD) do { \
  const float* b0_ = (LD); \
  const float* b1_ = (LD) + 1024; \
  const float* b2_ = (LD) + 2048; \
  const float* b3_ = (LD) + 3072; \
  ALOAD(BUF[0][0], b0_, "0");    ALOAD(BUF[0][1], b0_, "16"); \
  ALOAD(BUF[1][0], b0_, "2048"); ALOAD(BUF[1][1], b0_, "2064"); \
  ALOAD(BUF[2][0], b1_, "0");    ALOAD(BUF[2][1], b1_, "16"); \
  ALOAD(BUF[3][0], b1_, "2048"); ALOAD(BUF[3][1], b1_, "2064"); \
  ALOAD(BUF[4][0], b2_, "0");    ALOAD(BUF[4][1], b2_, "16"); \
  ALOAD(BUF[5][0], b2_, "2048"); ALOAD(BUF[5][1], b2_, "2064"); \
  ALOAD(BUF[6][0], b3_, "0");    ALOAD(BUF[6][1], b3_, "16"); \
  ALOAD(BUF[7][0], b3_, "2048"); ALOAD(BUF[7][1], b3_, "2064"); } while (0)

// even step: update aw in place
#define STEP_E(V0, V1) do { \
  float pp[8] = {(V0)[0], (V0)[1], (V0)[2], (V0)[3], (V1)[0], (V1)[1], (V1)[2], (V1)[3]}; \
  float cc[8]; \
  _Pragma("unroll") for (int i_ = 0; i_ < 8; ++i_) \
    cc[i_] = __builtin_fmaf(-aw[i_], pp[i_], aw[i_]); \
  float cL_ = __shfl_up(cc[7], 1); \
  float nw0_ = __builtin_fmaf(aw[0], pp[0], cL_ * m0f); \
  _Pragma("unroll") for (int i_ = 7; i_ >= 1; --i_) \
    aw[i_] = __builtin_fmaf(aw[i_], pp[i_], cc[i_ - 1]); \
  aw[0] = nw0_; } while (0)

// odd step: compute into nw, pack pairs (aw=even result, nw=odd result) into dw[q][X]
#define STEP_O(V0, V1, X) do { \
  float pp[8] = {(V0)[0], (V0)[1], (V0)[2], (V0)[3], (V1)[0], (V1)[1], (V1)[2], (V1)[3]}; \
  float cc[8], nw[8]; \
  _Pragma("unroll") for (int i_ = 0; i_ < 8; ++i_) \
    cc[i_] = __builtin_fmaf(-aw[i_], pp[i_], aw[i_]); \
  float cL_ = __shfl_up(cc[7], 1); \
  nw[0] = __builtin_fmaf(aw[0], pp[0], cL_ * m0f); \
  _Pragma("unroll") for (int i_ = 1; i_ < 8; ++i_) \
    nw[i_] = __builtin_fmaf(aw[i_], pp[i_], cc[i_ - 1]); \
  _Pragma("unroll") for (int i_ = 0; i_ < 8; ++i_) { \
    CVTPK(dw[i_][X], aw[i_], nw[i_]); aw[i_] = nw[i_]; } } while (0)

// 8 steps + 8 transposed b128 stores (rows = this lane's 8 q's, cols = 8 k's)
#define COMPUTE_CHUNK(BUF, OB0, OB1, OB2, OB3) do { \
  unsigned dw[8][4]; \
  STEP_E(BUF[0][0], BUF[0][1]); STEP_O(BUF[1][0], BUF[1][1], 0); \
  STEP_E(BUF[2][0], BUF[2][1]); STEP_O(BUF[3][0], BUF[3][1], 1); \
  STEP_E(BUF[4][0], BUF[4][1]); STEP_O(BUF[5][0], BUF[5][1], 2); \
  STEP_E(BUF[6][0], BUF[6][1]); STEP_O(BUF[7][0], BUF[7][1], 3); \
  u32x4 s_; \
  s_[0] = dw[0][0]; s_[1] = dw[0][1]; s_[2] = dw[0][2]; s_[3] = dw[0][3]; \
  ASTORE16(OB0, "0", s_); \
  s_[0] = dw[1][0]; s_[1] = dw[1][1]; s_[2] = dw[1][2]; s_[3] = dw[1][3]; \
  ASTORE16(OB0, "2048", s_); \
  s_[0] = dw[2][0]; s_[1] = dw[2][1]; s_[2] = dw[2][2]; s_[3] = dw[2][3]; \
  ASTORE16(OB1, "0", s_); \
  s_[0] = dw[3][0]; s_[1] = dw[3][1]; s_[2] = dw[3][2]; s_[3] = dw[3][3]; \
  ASTORE16(OB1, "2048", s_); \
  s_[0] = dw[4][0]; s_[1] = dw[4][1]; s_[2] = dw[4][2]; s_[3] = dw[4][3]; \
  ASTORE16(OB2, "0", s_); \
  s_[0] = dw[5][0]; s_[1] = dw[5][1]; s_[2] = dw[5][2]; s_[3] = dw[5][3]; \
  ASTORE16(OB2, "2048", s_); \
  s_[0] = dw[6][0]; s_[1] = dw[6][1]; s_[2] = dw[6][2]; s_[3] = dw[6][3]; \
  ASTORE16(OB3, "0", s_); \
  s_[0] = dw[7][0]; s_[1] = dw[7][1]; s_[2] = dw[7][2]; s_[3] = dw[7][3]; \
  ASTORE16(OB3, "2048", s_); } while (0)

__global__ __launch_bounds__(64, 1) void smma_scan_wave(const float* __restrict__ pT,
                                                        u16* __restrict__ amt) {
  const int b = blockIdx.x, lane = threadIdx.x;
  const float* ld = pT + (size_t)b * KL * QL + lane * 8;
  u16* ob0 = amt + (size_t)b * QL * KL + (size_t)(lane * 8) * KL;      // rows q=lane*8+{0,1}
  u16* ob1 = ob0 + 2 * KL;                                             // q+{2,3}
  u16* ob2 = ob0 + 4 * KL;                                             // q+{4,5}
  u16* ob3 = ob0 + 6 * KL;                                             // q+{6,7}
  const float m0f = (lane == 0) ? 0.f : 1.f;
  float aw[8];
  #pragma unroll
  for (int i = 0; i < 8; ++i) aw[i] = 0.f;
  if (lane == 0) aw[0] = 1.f;

  f32x4 A[8][2], B[8][2];
  LOAD_CHUNK(A, ld); ld += 8 * QL;      // chunk 0
  LOAD_CHUNK(B, ld); ld += 8 * QL;      // chunk 1

  // peeled first double-chunk
  WAITVM("16");
  COMPUTE_CHUNK(A, ob0, ob1, ob2, ob3);
  ob0 += 8; ob1 += 8; ob2 += 8; ob3 += 8;
  LOAD_CHUNK(A, ld); ld += 8 * QL;      // chunk 2
  WAITVM("24");
  COMPUTE_CHUNK(B, ob0, ob1, ob2, ob3);
  ob0 += 8; ob1 += 8; ob2 += 8; ob3 += 8;
  LOAD_CHUNK(B, ld); ld += 8 * QL;      // chunk 3

  for (int t = 1; t < 64; ++t) {
    WAITVM("24");
    COMPUTE_CHUNK(A, ob0, ob1, ob2, ob3);
    ob0 += 8; ob1 += 8; ob2 += 8; ob3 += 8;
    LOAD_CHUNK(A, ld); ld += 8 * QL;    // over-reads <=16 rows past end: 64KB slack after pT
    WAITVM("24");
    COMPUTE_CHUNK(B, ob0, ob1, ob2, ob3);
    ob0 += 8; ob1 += 8; ob2 += 8; ob3 += 8;
    LOAD_CHUNK(B, ld); ld += 8 * QL;
  }
}

// ---------------- batched bf16 transpose: dst[c][r] = src[r][c] ----------------
__global__ __launch_bounds__(256) void transpose_bf16(
    const u16* __restrict__ src, u16* __restrict__ dst, int R, int C, long sz)
{
  __shared__ __align__(16) u16 tile[64][72];
  src += (size_t)blockIdx.z * sz;
  dst += (size_t)blockIdx.z * sz;
  const int r0 = blockIdx.x * 64, c0 = blockIdx.y * 64;
  {
    const int rr = threadIdx.x >> 3, c8 = (threadIdx.x & 7) * 8;
    #pragma unroll
    for (int p = 0; p < 2; ++p)
      *(uint4*)&tile[rr + p * 32][c8] =
          *(const uint4*)&src[(size_t)(r0 + rr + p * 32) * C + c0 + c8];
  }
  __syncthreads();
  {
    const int cc = threadIdx.x & 31, r8 = (threadIdx.x >> 5) * 8;
    #pragma unroll
    for (int p = 0; p < 2; ++p) {
      union { u16 h[8]; uint4 v; } o;
      #pragma unroll
      for (int j = 0; j < 8; ++j) o.h[j] = tile[r8 + j][cc + p * 32];
      *(uint4*)&dst[(size_t)(c0 + cc + p * 32) * R + r0 + r8] = o.v;
    }
  }
}

// ---------------- universal NT MFMA GEMM ----------------
template <bool OUT_BF16, bool BIAS>
__global__ __launch_bounds__(256) void gemm_nt(
    const u16* __restrict__ Aw, const u16* __restrict__ Bw,
    void* __restrict__ Cptr, const float* __restrict__ bias,
    int lda, int ldb, int ldc, int K, float alpha, int zdiv,
    long sA1, long sA0, long sB1, long sB0, long sC1, long sC0)
{
  __shared__ __align__(16) u16 As[128][72];
  __shared__ __align__(16) u16 Bs[128][72];
  const int tid = threadIdx.x;
  const int z = blockIdx.z;
  const int z1 = z / zdiv, z0 = z % zdiv;
  const int m0 = blockIdx.x * 128, n0 = blockIdx.y * 128;
  const u16* Ab = Aw + z1 * sA1 + z0 * sA0;
  const u16* Bz = Bw + z1 * sB1 + z0 * sB0;

  f32x4 acc[4][4];
  const f32x4 zero4 = {0.f, 0.f, 0.f, 0.f};
  #pragma unroll
  for (int m = 0; m < 4; ++m)
    #pragma unroll
    for (int n = 0; n < 4; ++n) acc[m][n] = zero4;

  const int rs = tid >> 3;
  const int k8 = (tid & 7) * 8;
  const int wv_ = tid >> 6, lane = tid & 63;
  const int wr = (wv_ >> 1) * 64, wc = (wv_ & 1) * 64;
  const int fr = lane & 15, fk = (lane >> 4) * 8;

  for (int k0 = 0; k0 < K; k0 += 64) {
    #pragma unroll
    for (int p = 0; p < 4; ++p)
      *(uint4*)&As[rs + p * 32][k8] =
          *(const uint4*)&Ab[(size_t)(m0 + rs + p * 32) * lda + k0 + k8];
    #pragma unroll
    for (int p = 0; p < 4; ++p)
      *(uint4*)&Bs[rs + p * 32][k8] =
          *(const uint4*)&Bz[(size_t)(n0 + rs + p * 32) * ldb + k0 + k8];
    __syncthreads();
    #pragma unroll
    for (int ks = 0; ks < 2; ++ks) {
      bf16x8 av[4], bv_[4];
      #pragma unroll
      for (int m = 0; m < 4; ++m)
        av[m] = *(const bf16x8*)&As[wr + m * 16 + fr][ks * 32 + fk];
      #pragma unroll
      for (int n = 0; n < 4; ++n)
        bv_[n] = *(const bf16x8*)&Bs[wc + n * 16 + fr][ks * 32 + fk];
      #pragma unroll
      for (int m = 0; m < 4; ++m)
        #pragma unroll
        for (int n = 0; n < 4; ++n)
          acc[m][n] = __builtin_amdgcn_mfma_f32_16x16x32_bf16(av[m], bv_[n], acc[m][n], 0, 0, 0);
    }
    __syncthreads();
  }

  const int crow = (lane >> 4) * 4;
  const long cbase = z1 * sC1 + z0 * sC0;
  #pragma unroll
  for (int m = 0; m < 4; ++m) {
    #pragma unroll
    for (int n = 0; n < 4; ++n) {
      const int gm = m0 + wr + m * 16 + crow;
      const int gn = n0 + wc + n * 16 + fr;
      float bval = 0.f;
      if constexpr (BIAS) bval = bias[gn];
      #pragma unroll
      for (int j = 0; j < 4; ++j) {
        float vv = acc[m][n][j] * alpha + bval;
        if constexpr (OUT_BF16)
          ((u16*)Cptr)[cbase + (size_t)(gm + j) * ldc + gn] = f2b(vv);
        else
          ((float*)Cptr)[cbase + (size_t)(gm + j) * ldc + gn] = vv;
      }
    }
  }
}

extern "C" void kernel_launch(void* const* d_in, const int* in_sizes, int n_in,
                              void* d_out, int out_size, void* d_ws, size_t ws_size,
                              hipStream_t stream) {
  const float* q      = (const float*)d_in[0];
  const float* k      = (const float*)d_in[1];
  const float* v      = (const float*)d_in[2];
  const int*   mel    = (const int*)d_in[3];
  const float* w_qs   = (const float*)d_in[4];
  const float* b_qs   = (const float*)d_in[5];
  const float* w_ks   = (const float*)d_in[6];
  const float* b_ks   = (const float*)d_in[7];
  const float* w_vs   = (const float*)d_in[8];
  const float* b_vs   = (const float*)d_in[9];
  const float* w_last = (const float*)d_in[10];
  const float* b_last = (const float*)d_in[11];

  char* ws = (char*)d_ws;
  float* out = (float*)d_out;

  u16* W2Q = (u16*)(ws + B_W2Q);
  u16* W2K = (u16*)(ws + B_W2K);
  u16* W2V = (u16*)(ws + B_W2V);
  u16* WLB = (u16*)(ws + B_WLB);
  u16* QH  = (u16*)(ws + B_QH);
  u16* KH  = (u16*)(ws + B_KH);
  u16* VH  = (u16*)(ws + B_VH);
  u16* E   = (u16*)(ws + B_E);
  u16* AMT = (u16*)(ws + B_AMT);
  float* MS = (float*)(ws + B_MS);
  float* CPART = (float*)(ws + B_CPART);
  float* FRR = (float*)(ws + B_FRR);
  int* HIDX = (int*)(ws + B_HIDX);
  float* PT = (float*)(ws + B_PT);
  u16* VHT = (u16*)(ws + B_VHT);
  u16* CVP = (u16*)(ws + B_CVP);

  // 1. weight repacks (swizzled)
  repack_all<<<dim3(2496, 1, 4), 256, 0, stream>>>(w_qs, w_ks, w_vs, w_last,
                                                   W2Q, W2K, W2V, WLB);

  // 2. grouped convs: double-buffered weights, 1 barrier per K-step
  conv_mfma<<<dim3(128, 1, 9), 256, 0, stream>>>(q, k, v, W2Q, W2K, W2V,
                                                 b_qs, b_ks, b_vs, QH, KH, VH);

  // 3. e (bf16) + fused row-max
  qk_flash<<<dim3(4, 1, 48), 256, 0, stream>>>(QH, KH, E, MS);

  // 4. softmax denominators + colmax partials
  colsum_colmax<<<dim3(48, 8), 1024, 0, stream>>>(E, MS, CPART);

  // 5. fr + head select
  head_fr<<<NH * NB, 256, 0, stream>>>(CPART, FRR);
  select_head<<<1, 64, 0, stream>>>(FRR, mel, HIDX, out + OUT_FR);

  // 6. gather alpha_fc -> d_out, sigmoid -> pT [b][k][q]
  gather_fused<<<dim3(KL / 32, QL / 32, NB), dim3(32, 8), 0, stream>>>(
      E, MS, HIDX, out + OUT_ALPHA, PT);

  // 7. register scan -> AMT bf16 [b][q][k] directly (round-8 proven scan)
  smma_scan_wave<<<NB, 64, 0, stream>>>(PT, AMT);

  // 8. vh -> vhT [b][d][k]
  transpose_bf16<<<dim3(16, 6, NB), 256, 0, stream>>>(VH, VHT, KL, DM, 393216);

  // 9. cv_pre[b][q][d] = sum_k amT[q][k] * vhT[d][k]
  gemm_nt<true, false><<<dim3(4, 3, NB), 256, 0, stream>>>(
      AMT, VHT, CVP, nullptr, KL, KL, DM, KL, 1.f, 1,
      524288L, 0, 393216L, 0, 196608L, 0);

  // 10. out = cv_pre @ w_last^T + b_last
  gemm_nt<false, true><<<dim3(64, 3, 1), 256, 0, stream>>>(
      CVP, WLB, out + OUT_CV, b_last, DM, DM, DM, DM, 1.f, 1,
      0, 0, 0, 0, 0, 0);
}

// Round 13
// 295.746 us; speedup vs baseline: 1.0567x; 1.0567x over previous
//
#include <hip/hip_runtime.h>

#define NB 16
#define QL 512
#define KL 1024
#define DM 384
#define NH 3
#define DK 128

typedef unsigned short u16;
typedef __attribute__((ext_vector_type(8))) short bf16x8;
typedef __attribute__((ext_vector_type(4))) float f32x4;
typedef __attribute__((ext_vector_type(4))) unsigned int u32x4;

// ---------------- workspace byte offsets ----------------
static const size_t B_W2Q = 0;            // bf16 [384][1664] (granule-swizzled)
static const size_t B_W2K = 1277952;
static const size_t B_W2V = 2555904;
static const size_t B_WLB = 3833856;      // bf16 [384][384]
static const size_t B_QH  = 4128768;      // bf16 [16*512][384]
static const size_t B_KH  = 10420224;     // bf16 [16*1024][384]
static const size_t B_VH  = 23003136;     // bf16 [16*1024][384]
static const size_t B_E   = 67043328;     // bf16 [48][512][1024]
static const size_t B_AME = 67043328;     // f32 [16][1024][512] scan out (aliases dead E-low)
static const size_t B_AMT = 100597760;    // bf16 [16][512][1024] (aliases dead E-high)
static const size_t B_MS  = 117374976;    // f32 [48*512][2] {rowmax, inv}
static const size_t B_CPART = 117571584;  // f32 [48][8][1024]
static const size_t B_FRR = 119144448;    // f32 [48]
static const size_t B_HIDX = 119144704;   // int [16]
static const size_t B_PT  = 119144960;    // f32 [16][1024][512] (+64KB slack after)
static const size_t B_VHT = 152764928;    // bf16 [16][384][1024]
static const size_t B_CVP = 165347840;    // bf16 [16][512][384]

// d_out offsets (floats)
static const size_t OUT_CV    = 0;
static const size_t OUT_ALPHA = 3145728;
static const size_t OUT_FR    = 11534336;

__device__ __forceinline__ u16 f2b(float x) {
  union { float f; unsigned u; } q; q.f = x;
  unsigned r = q.u + 0x7fffu + ((q.u >> 16) & 1u);
  return (u16)(r >> 16);
}
__device__ __forceinline__ float b2f(u16 h) {
  union { unsigned u; float f; } q; q.u = ((unsigned)h) << 16;
  return q.f;
}

typedef __attribute__((address_space(3))) void lds_void;
typedef __attribute__((address_space(1))) const void g_void;
__device__ __forceinline__ void gload_lds16(const void* g, void* l) {
  __builtin_amdgcn_global_load_lds((g_void*)g, (lds_void*)l, 16, 0, 0);
}

// ---------------- weight repacks ----------------
__global__ __launch_bounds__(256) void repack_all(
    const float* __restrict__ wq, const float* __restrict__ wk,
    const float* __restrict__ wv, const float* __restrict__ wl,
    u16* __restrict__ dq, u16* __restrict__ dk, u16* __restrict__ dv,
    u16* __restrict__ dl) {
  const int z = blockIdx.z;
  const int tid = blockIdx.x * 256 + threadIdx.x;
  if (z < 3) {
    if (tid >= 384 * 1664) return;
    const float* src = (z == 0) ? wq : (z == 1) ? wk : wv;
    u16* dst = (z == 0) ? dq : (z == 1) ? dk : dv;
    const int oc = tid / 1664, k = tid % 1664;     // logical k
    const int t = k >> 7, ic = k & 127;
    const int g = (k >> 3) & 7, e = k & 7;
    const int pcol = (k & ~63) + (((g ^ (oc & 7))) << 3) + e;
    dst[(size_t)oc * 1664 + pcol] = f2b(src[(size_t)oc * 1664 + ic * 13 + t]);
  } else {
    if (tid < 384 * 384) dl[tid] = f2b(wl[tid]);
  }
}

// ---------------- grouped conv1d: 2-pass ic-split (round-8 proven form) ----------------
// z/3 selects tensor (0=q L=512, 1=k, 2=v L=1024); z%3 = group
__global__ __launch_bounds__(256, 4) void conv_mfma(
    const float* __restrict__ xq, const float* __restrict__ xk, const float* __restrict__ xv,
    const u16* __restrict__ wq, const u16* __restrict__ wk, const u16* __restrict__ wv,
    const float* __restrict__ bq, const float* __restrict__ bk, const float* __restrict__ bv,
    u16* __restrict__ oq, u16* __restrict__ ok, u16* __restrict__ ov)
{
  __shared__ __align__(16) u16 xw[140][72];
  __shared__ __align__(16) u16 Bs[128 * 64];    // unpadded, granule-swizzled content
  const int z = blockIdx.z;
  const int which = z / 3, g = z % 3;
  const float* X; const u16* W; const float* bias; u16* out; int Lmask;
  if (which == 0)      { X = xq; W = wq; bias = bq; out = oq; Lmask = 511; }
  else if (which == 1) { X = xk; W = wk; bias = bk; out = ok; Lmask = 1023; }
  else                 { X = xv; W = wv; bias = bv; out = ov; Lmask = 1023; }
  const int m0 = blockIdx.x * 128;
  if (m0 >= NB * (Lmask + 1)) return;
  X += g * DK; W += (size_t)g * DK * 1664; bias += g * DK; out += g * DK;

  const int tid = threadIdx.x;
  const int l0 = m0 & Lmask, bbase = m0 & ~Lmask;

  const int wv_ = tid >> 6, lane = tid & 63;
  const int wr = (wv_ >> 1) * 64, wc = (wv_ & 1) * 64;
  const int fr = lane & 15, fk8 = (lane >> 4);
  const int srow = lane >> 3, sg = lane & 7;

  f32x4 acc[4][4];
  const f32x4 zero4 = {0.f, 0.f, 0.f, 0.f};
  #pragma unroll
  for (int m = 0; m < 4; ++m)
    #pragma unroll
    for (int n = 0; n < 4; ++n) acc[m][n] = zero4;

  for (int h = 0; h < 2; ++h) {
    __syncthreads();   // all reads of xw (prev pass) done
    // stage this pass's 140-row x 64-ic window, f32 -> bf16 in flight
    for (int i = tid; i < 140 * 16; i += 256) {
      const int r = i >> 4, c4 = (i & 15) * 4;
      const int l = l0 - 6 + r;
      float4 v = make_float4(0.f, 0.f, 0.f, 0.f);
      if ((unsigned)l <= (unsigned)Lmask)
        v = *(const float4*)&X[(size_t)(bbase + l) * DM + h * 64 + c4];
      union { u16 u[4]; uint2 d; } o;
      o.u[0] = f2b(v.x); o.u[1] = f2b(v.y); o.u[2] = f2b(v.z); o.u[3] = f2b(v.w);
      *(uint2*)&xw[r][c4] = o.d;
    }
    for (int t = 0; t < 13; ++t) {
      const int k0 = t * 128 + h * 64;
      __syncthreads();   // xw ready (t==0) / prior Bs reads done
      #pragma unroll
      for (int i = 0; i < 4; ++i) {
        const int ii = wv_ + i * 4;
        gload_lds16(&W[(size_t)(8 * ii + srow) * 1664 + k0 + sg * 8],
                    (char*)Bs + ii * 1024);
      }
      __syncthreads();   // compiler drains vmcnt before barrier
      #pragma unroll
      for (int ks = 0; ks < 2; ++ks) {
        bf16x8 av[4], bv_[4];
        #pragma unroll
        for (int m = 0; m < 4; ++m)
          av[m] = *(const bf16x8*)&xw[t + wr + m * 16 + fr][ks * 32 + fk8 * 8];
        #pragma unroll
        for (int n = 0; n < 4; ++n) {
          const int r = wc + n * 16 + fr;
          const int pg = (ks * 4 + fk8) ^ (fr & 7);
          bv_[n] = *(const bf16x8*)&Bs[r * 64 + pg * 8];
        }
        #pragma unroll
        for (int m = 0; m < 4; ++m)
          #pragma unroll
          for (int n = 0; n < 4; ++n)
            acc[m][n] = __builtin_amdgcn_mfma_f32_16x16x32_bf16(av[m], bv_[n], acc[m][n], 0, 0, 0);
      }
    }
  }

  const int crow = (lane >> 4) * 4;
  #pragma unroll
  for (int m = 0; m < 4; ++m) {
    #pragma unroll
    for (int n = 0; n < 4; ++n) {
      const int gm = m0 + wr + m * 16 + crow;
      const int gn = wc + n * 16 + fr;
      const float bval = bias[gn];
      #pragma unroll
      for (int j = 0; j < 4; ++j)
        out[(size_t)(gm + j) * DM + gn] = f2b(acc[m][n][j] + bval);
    }
  }
}

// ---------------- qk: E[z][q][k] = qh.kh/sqrt(128) (bf16 out) + fused row-max ----------------
__global__ __launch_bounds__(256) void qk_flash(
    const u16* __restrict__ QH, const u16* __restrict__ KH,
    u16* __restrict__ E, float* __restrict__ MS)
{
  __shared__ __align__(16) u16 As[128][136];
  __shared__ __align__(16) u16 Bs[128][136];
  __shared__ float rmx[2][128];
  const int tid = threadIdx.x;
  const int z = blockIdx.z, h = z >> 4, b = z & 15;
  const int m0 = blockIdx.x * 128;
  const u16* Ag = QH + ((size_t)b * QL + m0) * DM + h * DK;
  const u16* Bg = KH + (size_t)b * KL * DM + h * DK;
  u16* Ez = E + (size_t)z * QL * KL;

  for (int i = tid; i < 128 * 16; i += 256) {
    const int r = i >> 4, s = i & 15;
    *(uint4*)&As[r][s * 8] = *(const uint4*)&Ag[(size_t)r * DM + s * 8];
  }

  const int wv_ = tid >> 6, lane = tid & 63;
  const int wr = (wv_ >> 1) * 64, wc = (wv_ & 1) * 64;
  const int fr = lane & 15, fk = (lane >> 4) * 8;
  const int crow = (lane >> 4) * 4;
  const float sc = 0.08838834764831845f;

  float mx[4][4];
  #pragma unroll
  for (int m = 0; m < 4; ++m)
    #pragma unroll
    for (int j = 0; j < 4; ++j) mx[m][j] = -1e30f;

  for (int nt = 0; nt < 8; ++nt) {
    if (nt) __syncthreads();
    for (int i = tid; i < 128 * 16; i += 256) {
      const int r = i >> 4, s = i & 15;
      *(uint4*)&Bs[r][s * 8] = *(const uint4*)&Bg[(size_t)(nt * 128 + r) * DM + s * 8];
    }
    __syncthreads();

    f32x4 acc[4][4];
    const f32x4 zero4 = {0.f, 0.f, 0.f, 0.f};
    #pragma unroll
    for (int m = 0; m < 4; ++m)
      #pragma unroll
      for (int n = 0; n < 4; ++n) acc[m][n] = zero4;
    #pragma unroll
    for (int ks = 0; ks < 4; ++ks) {
      bf16x8 av[4], bv_[4];
      #pragma unroll
      for (int m = 0; m < 4; ++m)
        av[m] = *(const bf16x8*)&As[wr + m * 16 + fr][ks * 32 + fk];
      #pragma unroll
      for (int n = 0; n < 4; ++n)
        bv_[n] = *(const bf16x8*)&Bs[wc + n * 16 + fr][ks * 32 + fk];
      #pragma unroll
      for (int m = 0; m < 4; ++m)
        #pragma unroll
        for (int n = 0; n < 4; ++n)
          acc[m][n] = __builtin_amdgcn_mfma_f32_16x16x32_bf16(av[m], bv_[n], acc[m][n], 0, 0, 0);
    }
    #pragma unroll
    for (int m = 0; m < 4; ++m) {
      #pragma unroll
      for (int n = 0; n < 4; ++n) {
        const int gm = m0 + wr + m * 16 + crow;
        const int gn = nt * 128 + wc + n * 16 + fr;
        #pragma unroll
        for (int j = 0; j < 4; ++j) {
          const float vv = acc[m][n][j] * sc;
          mx[m][j] = fmaxf(mx[m][j], vv);
          Ez[(size_t)(gm + j) * KL + gn] = f2b(vv);
        }
      }
    }
  }

  #pragma unroll
  for (int m = 0; m < 4; ++m)
    #pragma unroll
    for (int j = 0; j < 4; ++j) {
      #pragma unroll
      for (int off = 1; off < 16; off <<= 1)
        mx[m][j] = fmaxf(mx[m][j], __shfl_xor(mx[m][j], off));
    }
  if ((lane & 15) == 0) {
    #pragma unroll
    for (int m = 0; m < 4; ++m)
      #pragma unroll
      for (int j = 0; j < 4; ++j)
        rmx[wv_ & 1][wr + m * 16 + crow + j] = mx[m][j];
  }
  __syncthreads();
  if (tid < 128)
    MS[2 * ((size_t)z * QL + m0 + tid)] = fmaxf(rmx[0][tid], rmx[1][tid]);
}

// ---------------- per (z,qc): softmax denominators + column-max partials ----------
__global__ __launch_bounds__(1024) void colsum_colmax(
    const u16* __restrict__ E, float* __restrict__ MS, float* __restrict__ cpart)
{
  const int z = blockIdx.x, qc = blockIdx.y, kk = threadIdx.x;
  __shared__ float mq[64], wsum[64][17], invs[64];
  if (kk < 64) mq[kk] = MS[2 * ((size_t)z * QL + qc * 64 + kk)];
  __syncthreads();
  const u16* base = E + ((size_t)z * QL + qc * 64) * KL + kk;
  float ex[64];
  #pragma unroll
  for (int qq = 0; qq < 64; ++qq)
    ex[qq] = expf(b2f(base[(size_t)qq * KL]) - mq[qq]);
  const int wid = kk >> 6, lane = kk & 63;
  #pragma unroll
  for (int qq = 0; qq < 64; ++qq) {
    float s = ex[qq];
    #pragma unroll
    for (int off = 1; off < 64; off <<= 1) s += __shfl_xor(s, off);
    if (lane == 0) wsum[qq][wid] = s;
  }
  __syncthreads();
  if (kk < 64) {
    float s = 0.f;
    #pragma unroll
    for (int w = 0; w < 16; ++w) s += wsum[kk][w];
    const float inv = 1.f / s;
    invs[kk] = inv;
    MS[2 * ((size_t)z * QL + qc * 64 + kk) + 1] = inv;
  }
  __syncthreads();
  float cm = 0.f;
  #pragma unroll
  for (int qq = 0; qq < 64; ++qq) cm = fmaxf(cm, ex[qq] * invs[qq]);
  cpart[((size_t)z * 8 + qc) * KL + kk] = cm;
}

// ---------------- fr per (h,b): sum_k max over 8 q-chunks ----------------
__global__ __launch_bounds__(256) void head_fr(const float* __restrict__ cpart,
                                               float* __restrict__ frr) {
  const int z = blockIdx.x, tid = threadIdx.x;
  float s = 0.f;
  for (int k = tid; k < KL; k += 256) {
    float m = 0.f;
    #pragma unroll
    for (int c = 0; c < 8; ++c) m = fmaxf(m, cpart[((size_t)z * 8 + c) * KL + k]);
    s += m;
  }
  #pragma unroll
  for (int off = 32; off; off >>= 1) s += __shfl_xor(s, off);
  __shared__ float red[4];
  if ((tid & 63) == 0) red[tid >> 6] = s;
  __syncthreads();
  if (tid == 0) frr[z] = red[0] + red[1] + red[2] + red[3];
}

// ---------------- head select ----------------
__global__ void select_head(const float* __restrict__ frr, const int* __restrict__ mel,
                            int* __restrict__ hidx, float* __restrict__ fr_out) {
  __shared__ float bf[16];
  const int b = threadIdx.x;
  if (b < 16) {
    float best = -1e30f; int bh = 0;
    for (int h = 0; h < NH; ++h) {
      float fr = frr[h * 16 + b] / (float)mel[b];
      if (fr > best) { best = fr; bh = h; }
    }
    hidx[b] = bh;
    bf[b] = best;
  }
  __syncthreads();
  if (threadIdx.x == 0) {
    float s = 0.f;
    for (int i = 0; i < 16; ++i) s += bf[i];
    *fr_out = s / 16.f;
  }
}

// ---------------- gather selected head: alpha -> d_out; sigmoid(alpha)^T -> pT ----------------
__global__ __launch_bounds__(256) void gather_fused(
    const u16* __restrict__ E, const float* __restrict__ ms,
    const int* __restrict__ hidx, float* __restrict__ afc, float* __restrict__ pT)
{
  __shared__ float tile[32][33];
  const int b = blockIdx.z, k0 = blockIdx.x * 32, q0 = blockIdx.y * 32;
  const int hb = hidx[b];
  const u16* src = E + (size_t)(hb * 16 + b) * QL * KL;
  const float* msb = ms + 2 * ((size_t)(hb * 16 + b) * QL + q0);
  const int tx = threadIdx.x, ty = threadIdx.y;
  #pragma unroll
  for (int yy = 0; yy < 4; ++yy) {
    int r = ty + 8 * yy;
    float m = msb[2 * r], inv = msb[2 * r + 1];
    float v = expf(b2f(src[(size_t)(q0 + r) * KL + k0 + tx]) - m) * inv;
    afc[((size_t)b * QL + q0 + r) * KL + k0 + tx] = v;
    tile[r][tx] = v;
  }
  __syncthreads();
  #pragma unroll
  for (int yy = 0; yy < 4; ++yy) {
    int c = ty + 8 * yy;
    float v = tile[tx][c];
    pT[((size_t)b * KL + k0 + c) * QL + q0 + tx] = 1.f / (1.f + expf(-v));
  }
}

// ================= scan: asm prefetch + counted vmcnt, f32 coalesced [k][q] out ============
// (round-7 proven form, verbatim)
#define ALOAD(dst, base, OFF) \
  asm volatile("global_load_dwordx4 %0, %1, off offset:" OFF : "=v"(dst) : "v"(base))
#define ASTORE16(base, OFF, val) \
  asm volatile("global_store_dwordx4 %0, %1, off offset:" OFF :: "v"(base), "v"(val) : "memory")
#define WAITVM(N) do { \
  asm volatile("s_waitcnt vmcnt(" N ")" ::: "memory"); \
  __builtin_amdgcn_sched_barrier(0); } while (0)

// load 8 rows (16 dwordx4) starting at LD into BUF[8][2]
#define LOAD_CHUNK(BUF, LD) do { \
  const float* b0_ = (LD); \
  const float* b1_ = (LD) + 1024; \
  const float* b2_ = (LD) + 2048; \
  const float* b3_ = (LD) + 3072; \
  ALOAD(BUF[0][0], b0_, "0");    ALOAD(BUF[0][1], b0_, "16"); \
  ALOAD(BUF[1][0], b0_, "2048"); ALOAD(BUF[1][1], b0_, "2064"); \
  ALOAD(BUF[2][0], b1_, "0");    ALOAD(BUF[2][1], b1_, "16"); \
  ALOAD(BUF[3][0], b1_, "2048"); ALOAD(BUF[3][1], b1_, "2064"); \
  ALOAD(BUF[4][0], b2_, "0");    ALOAD(BUF[4][1], b2_, "16"); \
  ALOAD(BUF[5][0], b2_, "2048"); ALOAD(BUF[5][1], b2_, "2064"); \
  ALOAD(BUF[6][0], b3_, "0");    ALOAD(BUF[6][1], b3_, "16"); \
  ALOAD(BUF[7][0], b3_, "2048"); ALOAD(BUF[7][1], b3_, "2064"); } while (0)

// one scan step: p in (V0,V1); updates aw[8]; stores to SB at byte offsets O0/O1
#define STEP(V0, V1, SB, O0, O1) do { \
  float pp[8] = {(V0)[0], (V0)[1], (V0)[2], (V0)[3], (V1)[0], (V1)[1], (V1)[2], (V1)[3]}; \
  float cc[8]; \
  _Pragma("unroll") for (int i_ = 0; i_ < 8; ++i_) \
    cc[i_] = __builtin_fmaf(-aw[i_], pp[i_], aw[i_]); \
  float cL_ = __shfl_up(cc[7], 1); \
  float nw0_ = __builtin_fmaf(aw[0], pp[0], cL_ * m0f); \
  _Pragma("unroll") for (int i_ = 7; i_ >= 1; --i_) \
    aw[i_] = __builtin_fmaf(aw[i_], pp[i_], cc[i_ - 1]); \
  aw[0] = nw0_; \
  f32x4 s0_, s1_; \
  s0_[0] = aw[0]; s0_[1] = aw[1]; s0_[2] = aw[2]; s0_[3] = aw[3]; \
  s1_[0] = aw[4]; s1_[1] = aw[5]; s1_[2] = aw[6]; s1_[3] = aw[7]; \
  ASTORE16(SB, O0, s0_); ASTORE16(SB, O1, s1_); } while (0)

// compute+store 8 steps of BUF, outputs at OS (16 stores)
#define COMPUTE_CHUNK(BUF, OS) do { \
  float* o0_ = (OS); \
  float* o1_ = (OS) + 1024; \
  float* o2_ = (OS) + 2048; \
  float* o3_ = (OS) + 3072; \
  STEP(BUF[0][0], BUF[0][1], o0_, "0", "16"); \
  STEP(BUF[1][0], BUF[1][1], o0_, "2048", "2064"); \
  STEP(BUF[2][0], BUF[2][1], o1_, "0", "16"); \
  STEP(BUF[3][0], BUF[3][1], o1_, "2048", "2064"); \
  STEP(BUF[4][0], BUF[4][1], o2_, "0", "16"); \
  STEP(BUF[5][0], BUF[5][1], o2_, "2048", "2064"); \
  STEP(BUF[6][0], BUF[6][1], o3_, "0", "16"); \
  STEP(BUF[7][0], BUF[7][1], o3_, "2048", "2064"); } while (0)

__global__ __launch_bounds__(64, 1) void smma_scan_wave(const float* __restrict__ pT,
                                                        float* __restrict__ ame) {
  const int b = blockIdx.x, lane = threadIdx.x;
  const float* ld = pT + (size_t)b * KL * QL + lane * 8;
  float* os = ame + (size_t)b * KL * QL + lane * 8;
  const float m0f = (lane == 0) ? 0.f : 1.f;
  float aw[8];
  #pragma unroll
  for (int i = 0; i < 8; ++i) aw[i] = 0.f;
  if (lane == 0) aw[0] = 1.f;

  f32x4 A[8][2], B[8][2];
  LOAD_CHUNK(A, ld); ld += 8 * QL;      // chunk 0
  LOAD_CHUNK(B, ld); ld += 8 * QL;      // chunk 1

  // peeled first double-chunk (first wait sees only 2 chunks outstanding)
  WAITVM("16");
  COMPUTE_CHUNK(A, os); os += 8 * QL;
  LOAD_CHUNK(A, ld); ld += 8 * QL;      // chunk 2
  WAITVM("32");
  COMPUTE_CHUNK(B, os); os += 8 * QL;
  LOAD_CHUNK(B, ld); ld += 8 * QL;      // chunk 3

  for (int t = 1; t < 64; ++t) {
    WAITVM("32");
    COMPUTE_CHUNK(A, os); os += 8 * QL;
    LOAD_CHUNK(A, ld); ld += 8 * QL;    // over-reads <=16 rows past end: slack after PT
    WAITVM("32");
    COMPUTE_CHUNK(B, os); os += 8 * QL;
    LOAD_CHUNK(B, ld); ld += 8 * QL;
  }
}

// ---------------- transpose + convert: f32 [R][C] -> bf16 [C][R]  (round-7 proven) --------
__global__ __launch_bounds__(256) void transpose_cvt(
    const float* __restrict__ src, u16* __restrict__ dst, int R, int C) {
  __shared__ float tile[64][65];
  src += (size_t)blockIdx.z * R * C;
  dst += (size_t)blockIdx.z * R * C;
  const int r0 = blockIdx.x * 64, c0 = blockIdx.y * 64;
  {
    const int rr = threadIdx.x >> 4, cc = (threadIdx.x & 15) * 4;
    #pragma unroll
    for (int p = 0; p < 4; ++p) {
      float4 v = *(const float4*)&src[(size_t)(r0 + rr + p * 16) * C + c0 + cc];
      tile[rr + p * 16][cc] = v.x; tile[rr + p * 16][cc + 1] = v.y;
      tile[rr + p * 16][cc + 2] = v.z; tile[rr + p * 16][cc + 3] = v.w;
    }
  }
  __syncthreads();
  {
    const int oc = threadIdx.x >> 2, r8 = (threadIdx.x & 3) * 16;
    #pragma unroll
    for (int p = 0; p < 2; ++p) {
      union { u16 h[8]; uint4 u; } o;
      #pragma unroll
      for (int j = 0; j < 8; ++j) o.h[j] = f2b(tile[r8 + p * 8 + j][oc]);
      *(uint4*)&dst[(size_t)(c0 + oc) * R + r0 + r8 + p * 8] = o.u;
    }
  }
}

// ---------------- batched bf16 transpose: dst[c][r] = src[r][c] ----------------
__global__ __launch_bounds__(256) void transpose_bf16(
    const u16* __restrict__ src, u16* __restrict__ dst, int R, int C, long sz)
{
  __shared__ __align__(16) u16 tile[64][72];
  src += (size_t)blockIdx.z * sz;
  dst += (size_t)blockIdx.z * sz;
  const int r0 = blockIdx.x * 64, c0 = blockIdx.y * 64;
  {
    const int rr = threadIdx.x >> 3, c8 = (threadIdx.x & 7) * 8;
    #pragma unroll
    for (int p = 0; p < 2; ++p)
      *(uint4*)&tile[rr + p * 32][c8] =
          *(const uint4*)&src[(size_t)(r0 + rr + p * 32) * C + c0 + c8];
  }
  __syncthreads();
  {
    const int cc = threadIdx.x & 31, r8 = (threadIdx.x >> 5) * 8;
    #pragma unroll
    for (int p = 0; p < 2; ++p) {
      union { u16 h[8]; uint4 v; } o;
      #pragma unroll
      for (int j = 0; j < 8; ++j) o.h[j] = tile[r8 + j][cc + p * 32];
      *(uint4*)&dst[(size_t)(c0 + cc + p * 32) * R + r0 + r8] = o.v;
    }
  }
}

// ---------------- universal NT MFMA GEMM ----------------
template <bool OUT_BF16, bool BIAS>
__global__ __launch_bounds__(256) void gemm_nt(
    const u16* __restrict__ Aw, const u16* __restrict__ Bw,
    void* __restrict__ Cptr, const float* __restrict__ bias,
    int lda, int ldb, int ldc, int K, float alpha, int zdiv,
    long sA1, long sA0, long sB1, long sB0, long sC1, long sC0)
{
  __shared__ __align__(16) u16 As[128][72];
  __shared__ __align__(16) u16 Bs[128][72];
  const int tid = threadIdx.x;
  const int z = blockIdx.z;
  const int z1 = z / zdiv, z0 = z % zdiv;
  const int m0 = blockIdx.x * 128, n0 = blockIdx.y * 128;
  const u16* Ab = Aw + z1 * sA1 + z0 * sA0;
  const u16* Bz = Bw + z1 * sB1 + z0 * sB0;

  f32x4 acc[4][4];
  const f32x4 zero4 = {0.f, 0.f, 0.f, 0.f};
  #pragma unroll
  for (int m = 0; m < 4; ++m)
    #pragma unroll
    for (int n = 0; n < 4; ++n) acc[m][n] = zero4;

  const int rs = tid >> 3;
  const int k8 = (tid & 7) * 8;
  const int wv_ = tid >> 6, lane = tid & 63;
  const int wr = (wv_ >> 1) * 64, wc = (wv_ & 1) * 64;
  const int fr = lane & 15, fk = (lane >> 4) * 8;

  for (int k0 = 0; k0 < K; k0 += 64) {
    #pragma unroll
    for (int p = 0; p < 4; ++p)
      *(uint4*)&As[rs + p * 32][k8] =
          *(const uint4*)&Ab[(size_t)(m0 + rs + p * 32) * lda + k0 + k8];
    #pragma unroll
    for (int p = 0; p < 4; ++p)
      *(uint4*)&Bs[rs + p * 32][k8] =
          *(const uint4*)&Bz[(size_t)(n0 + rs + p * 32) * ldb + k0 + k8];
    __syncthreads();
    #pragma unroll
    for (int ks = 0; ks < 2; ++ks) {
      bf16x8 av[4], bv_[4];
      #pragma unroll
      for (int m = 0; m < 4; ++m)
        av[m] = *(const bf16x8*)&As[wr + m * 16 + fr][ks * 32 + fk];
      #pragma unroll
      for (int n = 0; n < 4; ++n)
        bv_[n] = *(const bf16x8*)&Bs[wc + n * 16 + fr][ks * 32 + fk];
      #pragma unroll
      for (int m = 0; m < 4; ++m)
        #pragma unroll
        for (int n = 0; n < 4; ++n)
          acc[m][n] = __builtin_amdgcn_mfma_f32_16x16x32_bf16(av[m], bv_[n], acc[m][n], 0, 0, 0);
    }
    __syncthreads();
  }

  const int crow = (lane >> 4) * 4;
  const long cbase = z1 * sC1 + z0 * sC0;
  #pragma unroll
  for (int m = 0; m < 4; ++m) {
    #pragma unroll
    for (int n = 0; n < 4; ++n) {
      const int gm = m0 + wr + m * 16 + crow;
      const int gn = n0 + wc + n * 16 + fr;
      float bval = 0.f;
      if constexpr (BIAS) bval = bias[gn];
      #pragma unroll
      for (int j = 0; j < 4; ++j) {
        float vv = acc[m][n][j] * alpha + bval;
        if constexpr (OUT_BF16)
          ((u16*)Cptr)[cbase + (size_t)(gm + j) * ldc + gn] = f2b(vv);
        else
          ((float*)Cptr)[cbase + (size_t)(gm + j) * ldc + gn] = vv;
      }
    }
  }
}

extern "C" void kernel_launch(void* const* d_in, const int* in_sizes, int n_in,
                              void* d_out, int out_size, void* d_ws, size_t ws_size,
                              hipStream_t stream) {
  const float* q      = (const float*)d_in[0];
  const float* k      = (const float*)d_in[1];
  const float* v      = (const float*)d_in[2];
  const int*   mel    = (const int*)d_in[3];
  const float* w_qs   = (const float*)d_in[4];
  const float* b_qs   = (const float*)d_in[5];
  const float* w_ks   = (const float*)d_in[6];
  const float* b_ks   = (const float*)d_in[7];
  const float* w_vs   = (const float*)d_in[8];
  const float* b_vs   = (const float*)d_in[9];
  const float* w_last = (const float*)d_in[10];
  const float* b_last = (const float*)d_in[11];

  char* ws = (char*)d_ws;
  float* out = (float*)d_out;

  u16* W2Q = (u16*)(ws + B_W2Q);
  u16* W2K = (u16*)(ws + B_W2K);
  u16* W2V = (u16*)(ws + B_W2V);
  u16* WLB = (u16*)(ws + B_WLB);
  u16* QH  = (u16*)(ws + B_QH);
  u16* KH  = (u16*)(ws + B_KH);
  u16* VH  = (u16*)(ws + B_VH);
  u16* E   = (u16*)(ws + B_E);
  float* AME = (float*)(ws + B_AME);
  u16* AMT = (u16*)(ws + B_AMT);
  float* MS = (float*)(ws + B_MS);
  float* CPART = (float*)(ws + B_CPART);
  float* FRR = (float*)(ws + B_FRR);
  int* HIDX = (int*)(ws + B_HIDX);
  float* PT = (float*)(ws + B_PT);
  u16* VHT = (u16*)(ws + B_VHT);
  u16* CVP = (u16*)(ws + B_CVP);

  // 1. weight repacks (swizzled)
  repack_all<<<dim3(2496, 1, 4), 256, 0, stream>>>(w_qs, w_ks, w_vs, w_last,
                                                   W2Q, W2K, W2V, WLB);

  // 2. grouped convs (round-8 proven ic-split form)
  conv_mfma<<<dim3(128, 1, 9), 256, 0, stream>>>(q, k, v, W2Q, W2K, W2V,
                                                 b_qs, b_ks, b_vs, QH, KH, VH);

  // 3. e (bf16) + fused row-max
  qk_flash<<<dim3(4, 1, 48), 256, 0, stream>>>(QH, KH, E, MS);

  // 4. softmax denominators + colmax partials
  colsum_colmax<<<dim3(48, 8), 1024, 0, stream>>>(E, MS, CPART);

  // 5. fr + head select
  head_fr<<<NH * NB, 256, 0, stream>>>(CPART, FRR);
  select_head<<<1, 64, 0, stream>>>(FRR, mel, HIDX, out + OUT_FR);

  // 6. gather alpha_fc -> d_out, sigmoid -> pT [b][k][q]
  gather_fused<<<dim3(KL / 32, QL / 32, NB), dim3(32, 8), 0, stream>>>(
      E, MS, HIDX, out + OUT_ALPHA, PT);

  // 7. register scan -> AME f32 [b][k][q] (coalesced; round-7 proven form)
  smma_scan_wave<<<NB, 64, 0, stream>>>(PT, AME);

  // 8. transposes: AME f32 -> AMT bf16 [b][q][k]; VH -> VHT [b][d][k]
  transpose_cvt<<<dim3(16, 8, NB), 256, 0, stream>>>(AME, AMT, KL, QL);
  transpose_bf16<<<dim3(16, 6, NB), 256, 0, stream>>>(VH, VHT, KL, DM, 393216);

  // 9. cv_pre[b][q][d] = sum_k amT[q][k] * vhT[d][k]
  gemm_nt<true, false><<<dim3(4, 3, NB), 256, 0, stream>>>(
      AMT, VHT, CVP, nullptr, KL, KL, DM, KL, 1.f, 1,
      524288L, 0, 393216L, 0, 196608L, 0);

  // 10. out = cv_pre @ w_last^T + b_last
  gemm_nt<false, true><<<dim3(64, 3, 1), 256, 0, stream>>>(
      CVP, WLB, out + OUT_CV, b_last, DM, DM, DM, DM, 1.f, 1,
      0, 0, 0, 0, 0, 0);
}

// Round 14
// 255.522 us; speedup vs baseline: 1.2230x; 1.1574x over previous
//
#include <hip/hip_runtime.h>

#define NB 16
#define QL 512
#define KL 1024
#define DM 384
#define NH 3
#define DK 128

typedef unsigned short u16;
typedef __attribute__((ext_vector_type(8))) short bf16x8;
typedef __attribute__((ext_vector_type(4))) float f32x4;
typedef __attribute__((ext_vector_type(4))) unsigned int u32x4;

// ---------------- workspace byte offsets ----------------
static const size_t B_W2Q = 0;            // bf16 [384][1664] (granule-swizzled)
static const size_t B_W2K = 1277952;
static const size_t B_W2V = 2555904;
static const size_t B_WLB = 3833856;      // bf16 [384][384]
static const size_t B_QH  = 4128768;      // bf16 [16*512][384]
static const size_t B_KH  = 10420224;     // bf16 [16*1024][384]
static const size_t B_VH  = 23003136;     // bf16 [16*1024][384]
static const size_t B_E   = 67043328;     // bf16 [48][512][1024]
static const size_t B_AME = 67043328;     // f32 [16][1024][512] scan out (aliases dead E-low)
static const size_t B_AMT = 100597760;    // bf16 [16][512][1024] (aliases dead E-high)
static const size_t B_MS  = 117374976;    // f32 [48*512][2] {rowmax, inv}
static const size_t B_CPART = 117571584;  // f32 [48][8][1024]
static const size_t B_FRR = 119144448;    // f32 [48]
static const size_t B_HIDX = 119144704;   // int [16]
static const size_t B_PT  = 119144960;    // f32 [16][1024][512] (+64KB slack after)
static const size_t B_VHT = 152764928;    // bf16 [16][384][1024]
static const size_t B_CVP = 165347840;    // bf16 [16][512][384]

// d_out offsets (floats)
static const size_t OUT_CV    = 0;
static const size_t OUT_ALPHA = 3145728;
static const size_t OUT_FR    = 11534336;

__device__ __forceinline__ u16 f2b(float x) {
  union { float f; unsigned u; } q; q.f = x;
  unsigned r = q.u + 0x7fffu + ((q.u >> 16) & 1u);
  return (u16)(r >> 16);
}
__device__ __forceinline__ float b2f(u16 h) {
  union { unsigned u; float f; } q; q.u = ((unsigned)h) << 16;
  return q.f;
}

typedef __attribute__((address_space(3))) void lds_void;
typedef __attribute__((address_space(1))) const void g_void;
__device__ __forceinline__ void gload_lds16(const void* g, void* l) {
  __builtin_amdgcn_global_load_lds((g_void*)g, (lds_void*)l, 16, 0, 0);
}

// ---------------- weight repacks ----------------
__global__ __launch_bounds__(256) void repack_all(
    const float* __restrict__ wq, const float* __restrict__ wk,
    const float* __restrict__ wv, const float* __restrict__ wl,
    u16* __restrict__ dq, u16* __restrict__ dk, u16* __restrict__ dv,
    u16* __restrict__ dl) {
  const int z = blockIdx.z;
  const int tid = blockIdx.x * 256 + threadIdx.x;
  if (z < 3) {
    if (tid >= 384 * 1664) return;
    const float* src = (z == 0) ? wq : (z == 1) ? wk : wv;
    u16* dst = (z == 0) ? dq : (z == 1) ? dk : dv;
    const int oc = tid / 1664, k = tid % 1664;     // logical k
    const int t = k >> 7, ic = k & 127;
    const int g = (k >> 3) & 7, e = k & 7;
    const int pcol = (k & ~63) + (((g ^ (oc & 7))) << 3) + e;
    dst[(size_t)oc * 1664 + pcol] = f2b(src[(size_t)oc * 1664 + ic * 13 + t]);
  } else {
    if (tid < 384 * 384) dl[tid] = f2b(wl[tid]);
  }
}

// ---------------- grouped conv1d: 2-pass ic-split (round-8 proven form) ----------------
// z/3 selects tensor (0=q L=512, 1=k, 2=v L=1024); z%3 = group
__global__ __launch_bounds__(256, 4) void conv_mfma(
    const float* __restrict__ xq, const float* __restrict__ xk, const float* __restrict__ xv,
    const u16* __restrict__ wq, const u16* __restrict__ wk, const u16* __restrict__ wv,
    const float* __restrict__ bq, const float* __restrict__ bk, const float* __restrict__ bv,
    u16* __restrict__ oq, u16* __restrict__ ok, u16* __restrict__ ov)
{
  __shared__ __align__(16) u16 xw[140][72];
  __shared__ __align__(16) u16 Bs[128 * 64];    // unpadded, granule-swizzled content
  const int z = blockIdx.z;
  const int which = z / 3, g = z % 3;
  const float* X; const u16* W; const float* bias; u16* out; int Lmask;
  if (which == 0)      { X = xq; W = wq; bias = bq; out = oq; Lmask = 511; }
  else if (which == 1) { X = xk; W = wk; bias = bk; out = ok; Lmask = 1023; }
  else                 { X = xv; W = wv; bias = bv; out = ov; Lmask = 1023; }
  const int m0 = blockIdx.x * 128;
  if (m0 >= NB * (Lmask + 1)) return;
  X += g * DK; W += (size_t)g * DK * 1664; bias += g * DK; out += g * DK;

  const int tid = threadIdx.x;
  const int l0 = m0 & Lmask, bbase = m0 & ~Lmask;

  const int wv_ = tid >> 6, lane = tid & 63;
  const int wr = (wv_ >> 1) * 64, wc = (wv_ & 1) * 64;
  const int fr = lane & 15, fk8 = (lane >> 4);
  const int srow = lane >> 3, sg = lane & 7;

  f32x4 acc[4][4];
  const f32x4 zero4 = {0.f, 0.f, 0.f, 0.f};
  #pragma unroll
  for (int m = 0; m < 4; ++m)
    #pragma unroll
    for (int n = 0; n < 4; ++n) acc[m][n] = zero4;

  for (int h = 0; h < 2; ++h) {
    __syncthreads();   // all reads of xw (prev pass) done
    // stage this pass's 140-row x 64-ic window, f32 -> bf16 in flight
    for (int i = tid; i < 140 * 16; i += 256) {
      const int r = i >> 4, c4 = (i & 15) * 4;
      const int l = l0 - 6 + r;
      float4 v = make_float4(0.f, 0.f, 0.f, 0.f);
      if ((unsigned)l <= (unsigned)Lmask)
        v = *(const float4*)&X[(size_t)(bbase + l) * DM + h * 64 + c4];
      union { u16 u[4]; uint2 d; } o;
      o.u[0] = f2b(v.x); o.u[1] = f2b(v.y); o.u[2] = f2b(v.z); o.u[3] = f2b(v.w);
      *(uint2*)&xw[r][c4] = o.d;
    }
    for (int t = 0; t < 13; ++t) {
      const int k0 = t * 128 + h * 64;
      __syncthreads();   // xw ready (t==0) / prior Bs reads done
      #pragma unroll
      for (int i = 0; i < 4; ++i) {
        const int ii = wv_ + i * 4;
        gload_lds16(&W[(size_t)(8 * ii + srow) * 1664 + k0 + sg * 8],
                    (char*)Bs + ii * 1024);
      }
      __syncthreads();   // compiler drains vmcnt before barrier
      #pragma unroll
      for (int ks = 0; ks < 2; ++ks) {
        bf16x8 av[4], bv_[4];
        #pragma unroll
        for (int m = 0; m < 4; ++m)
          av[m] = *(const bf16x8*)&xw[t + wr + m * 16 + fr][ks * 32 + fk8 * 8];
        #pragma unroll
        for (int n = 0; n < 4; ++n) {
          const int r = wc + n * 16 + fr;
          const int pg = (ks * 4 + fk8) ^ (fr & 7);
          bv_[n] = *(const bf16x8*)&Bs[r * 64 + pg * 8];
        }
        #pragma unroll
        for (int m = 0; m < 4; ++m)
          #pragma unroll
          for (int n = 0; n < 4; ++n)
            acc[m][n] = __builtin_amdgcn_mfma_f32_16x16x32_bf16(av[m], bv_[n], acc[m][n], 0, 0, 0);
      }
    }
  }

  const int crow = (lane >> 4) * 4;
  #pragma unroll
  for (int m = 0; m < 4; ++m) {
    #pragma unroll
    for (int n = 0; n < 4; ++n) {
      const int gm = m0 + wr + m * 16 + crow;
      const int gn = wc + n * 16 + fr;
      const float bval = bias[gn];
      #pragma unroll
      for (int j = 0; j < 4; ++j)
        out[(size_t)(gm + j) * DM + gn] = f2b(acc[m][n][j] + bval);
    }
  }
}

// ---------------- qk: E[z][q][k] = qh.kh/sqrt(128) (bf16 out) + fused row-max ----------------
__global__ __launch_bounds__(256) void qk_flash(
    const u16* __restrict__ QH, const u16* __restrict__ KH,
    u16* __restrict__ E, float* __restrict__ MS)
{
  __shared__ __align__(16) u16 As[128][136];
  __shared__ __align__(16) u16 Bs[128][136];
  __shared__ float rmx[2][128];
  const int tid = threadIdx.x;
  const int z = blockIdx.z, h = z >> 4, b = z & 15;
  const int m0 = blockIdx.x * 128;
  const u16* Ag = QH + ((size_t)b * QL + m0) * DM + h * DK;
  const u16* Bg = KH + (size_t)b * KL * DM + h * DK;
  u16* Ez = E + (size_t)z * QL * KL;

  for (int i = tid; i < 128 * 16; i += 256) {
    const int r = i >> 4, s = i & 15;
    *(uint4*)&As[r][s * 8] = *(const uint4*)&Ag[(size_t)r * DM + s * 8];
  }

  const int wv_ = tid >> 6, lane = tid & 63;
  const int wr = (wv_ >> 1) * 64, wc = (wv_ & 1) * 64;
  const int fr = lane & 15, fk = (lane >> 4) * 8;
  const int crow = (lane >> 4) * 4;
  const float sc = 0.08838834764831845f;

  float mx[4][4];
  #pragma unroll
  for (int m = 0; m < 4; ++m)
    #pragma unroll
    for (int j = 0; j < 4; ++j) mx[m][j] = -1e30f;

  for (int nt = 0; nt < 8; ++nt) {
    if (nt) __syncthreads();
    for (int i = tid; i < 128 * 16; i += 256) {
      const int r = i >> 4, s = i & 15;
      *(uint4*)&Bs[r][s * 8] = *(const uint4*)&Bg[(size_t)(nt * 128 + r) * DM + s * 8];
    }
    __syncthreads();

    f32x4 acc[4][4];
    const f32x4 zero4 = {0.f, 0.f, 0.f, 0.f};
    #pragma unroll
    for (int m = 0; m < 4; ++m)
      #pragma unroll
      for (int n = 0; n < 4; ++n) acc[m][n] = zero4;
    #pragma unroll
    for (int ks = 0; ks < 4; ++ks) {
      bf16x8 av[4], bv_[4];
      #pragma unroll
      for (int m = 0; m < 4; ++m)
        av[m] = *(const bf16x8*)&As[wr + m * 16 + fr][ks * 32 + fk];
      #pragma unroll
      for (int n = 0; n < 4; ++n)
        bv_[n] = *(const bf16x8*)&Bs[wc + n * 16 + fr][ks * 32 + fk];
      #pragma unroll
      for (int m = 0; m < 4; ++m)
        #pragma unroll
        for (int n = 0; n < 4; ++n)
          acc[m][n] = __builtin_amdgcn_mfma_f32_16x16x32_bf16(av[m], bv_[n], acc[m][n], 0, 0, 0);
    }
    #pragma unroll
    for (int m = 0; m < 4; ++m) {
      #pragma unroll
      for (int n = 0; n < 4; ++n) {
        const int gm = m0 + wr + m * 16 + crow;
        const int gn = nt * 128 + wc + n * 16 + fr;
        #pragma unroll
        for (int j = 0; j < 4; ++j) {
          const float vv = acc[m][n][j] * sc;
          mx[m][j] = fmaxf(mx[m][j], vv);
          Ez[(size_t)(gm + j) * KL + gn] = f2b(vv);
        }
      }
    }
  }

  #pragma unroll
  for (int m = 0; m < 4; ++m)
    #pragma unroll
    for (int j = 0; j < 4; ++j) {
      #pragma unroll
      for (int off = 1; off < 16; off <<= 1)
        mx[m][j] = fmaxf(mx[m][j], __shfl_xor(mx[m][j], off));
    }
  if ((lane & 15) == 0) {
    #pragma unroll
    for (int m = 0; m < 4; ++m)
      #pragma unroll
      for (int j = 0; j < 4; ++j)
        rmx[wv_ & 1][wr + m * 16 + crow + j] = mx[m][j];
  }
  __syncthreads();
  if (tid < 128)
    MS[2 * ((size_t)z * QL + m0 + tid)] = fmaxf(rmx[0][tid], rmx[1][tid]);
}

// ---------------- per (z,qc): softmax denominators + column-max partials -------------------
// 8 waves; wave w owns rows {w, w+8, ..., w+56}; lane owns cols {lane*8..+8, 512+lane*8..+8}.
// Spill-free: only cm[16] persists across rows.
__global__ __launch_bounds__(512) void colsum_colmax(
    const u16* __restrict__ E, float* __restrict__ MS, float* __restrict__ cpart)
{
  __shared__ float cm_s[8][1024];
  const int z = blockIdx.x, qc = blockIdx.y;
  const int tid = threadIdx.x;
  const int w = tid >> 6, lane = tid & 63;
  const u16* base = E + ((size_t)z * QL + qc * 64) * KL;
  const size_t msrow = (size_t)z * QL + qc * 64;

  float cm[16];
  #pragma unroll
  for (int j = 0; j < 16; ++j) cm[j] = 0.f;

  for (int r8 = 0; r8 < 8; ++r8) {
    const int r = w + 8 * r8;
    const float m = MS[2 * (msrow + r)];
    union { u16 h[8]; uint4 v; } a, b;
    a.v = *(const uint4*)&base[(size_t)r * KL + lane * 8];
    b.v = *(const uint4*)&base[(size_t)r * KL + 512 + lane * 8];
    float ex[16];
    #pragma unroll
    for (int j = 0; j < 8; ++j) {
      ex[j] = expf(b2f(a.h[j]) - m);
      ex[8 + j] = expf(b2f(b.h[j]) - m);
    }
    float s = 0.f;
    #pragma unroll
    for (int j = 0; j < 16; ++j) s += ex[j];
    #pragma unroll
    for (int off = 32; off; off >>= 1) s += __shfl_xor(s, off);
    const float inv = 1.f / s;
    if (lane == 0) MS[2 * (msrow + r) + 1] = inv;
    #pragma unroll
    for (int j = 0; j < 16; ++j) cm[j] = fmaxf(cm[j], ex[j] * inv);
  }

  #pragma unroll
  for (int j = 0; j < 8; ++j) {
    cm_s[w][lane * 8 + j] = cm[j];
    cm_s[w][512 + lane * 8 + j] = cm[8 + j];
  }
  __syncthreads();
  for (int c = tid; c < 1024; c += 512) {
    float m = 0.f;
    #pragma unroll
    for (int w2 = 0; w2 < 8; ++w2) m = fmaxf(m, cm_s[w2][c]);
    cpart[((size_t)z * 8 + qc) * KL + c] = m;
  }
}

// ---------------- fr per (h,b): sum_k max over 8 q-chunks ----------------
__global__ __launch_bounds__(256) void head_fr(const float* __restrict__ cpart,
                                               float* __restrict__ frr) {
  const int z = blockIdx.x, tid = threadIdx.x;
  float s = 0.f;
  for (int k = tid; k < KL; k += 256) {
    float m = 0.f;
    #pragma unroll
    for (int c = 0; c < 8; ++c) m = fmaxf(m, cpart[((size_t)z * 8 + c) * KL + k]);
    s += m;
  }
  #pragma unroll
  for (int off = 32; off; off >>= 1) s += __shfl_xor(s, off);
  __shared__ float red[4];
  if ((tid & 63) == 0) red[tid >> 6] = s;
  __syncthreads();
  if (tid == 0) frr[z] = red[0] + red[1] + red[2] + red[3];
}

// ---------------- head select ----------------
__global__ void select_head(const float* __restrict__ frr, const int* __restrict__ mel,
                            int* __restrict__ hidx, float* __restrict__ fr_out) {
  __shared__ float bf[16];
  const int b = threadIdx.x;
  if (b < 16) {
    float best = -1e30f; int bh = 0;
    for (int h = 0; h < NH; ++h) {
      float fr = frr[h * 16 + b] / (float)mel[b];
      if (fr > best) { best = fr; bh = h; }
    }
    hidx[b] = bh;
    bf[b] = best;
  }
  __syncthreads();
  if (threadIdx.x == 0) {
    float s = 0.f;
    for (int i = 0; i < 16; ++i) s += bf[i];
    *fr_out = s / 16.f;
  }
}

// ---------------- gather selected head: alpha -> d_out; sigmoid(alpha)^T -> pT ----------------
__global__ __launch_bounds__(256) void gather_fused(
    const u16* __restrict__ E, const float* __restrict__ ms,
    const int* __restrict__ hidx, float* __restrict__ afc, float* __restrict__ pT)
{
  __shared__ float tile[32][33];
  const int b = blockIdx.z, k0 = blockIdx.x * 32, q0 = blockIdx.y * 32;
  const int hb = hidx[b];
  const u16* src = E + (size_t)(hb * 16 + b) * QL * KL;
  const float* msb = ms + 2 * ((size_t)(hb * 16 + b) * QL + q0);
  const int tx = threadIdx.x, ty = threadIdx.y;
  #pragma unroll
  for (int yy = 0; yy < 4; ++yy) {
    int r = ty + 8 * yy;
    float m = msb[2 * r], inv = msb[2 * r + 1];
    float v = expf(b2f(src[(size_t)(q0 + r) * KL + k0 + tx]) - m) * inv;
    afc[((size_t)b * QL + q0 + r) * KL + k0 + tx] = v;
    tile[r][tx] = v;
  }
  __syncthreads();
  #pragma unroll
  for (int yy = 0; yy < 4; ++yy) {
    int c = ty + 8 * yy;
    float v = tile[tx][c];
    pT[((size_t)b * KL + k0 + c) * QL + q0 + tx] = 1.f / (1.f + expf(-v));
  }
}

// ================= scan: asm prefetch + counted vmcnt, f32 coalesced [k][q] out ============
// (round-7 proven form, verbatim)
#define ALOAD(dst, base, OFF) \
  asm volatile("global_load_dwordx4 %0, %1, off offset:" OFF : "=v"(dst) : "v"(base))
#define ASTORE16(base, OFF, val) \
  asm volatile("global_store_dwordx4 %0, %1, off offset:" OFF :: "v"(base), "v"(val) : "memory")
#define WAITVM(N) do { \
  asm volatile("s_waitcnt vmcnt(" N ")" ::: "memory"); \
  __builtin_amdgcn_sched_barrier(0); } while (0)

// load 8 rows (16 dwordx4) starting at LD into BUF[8][2]
#define LOAD_CHUNK(BUF, LD) do { \
  const float* b0_ = (LD); \
  const float* b1_ = (LD) + 1024; \
  const float* b2_ = (LD) + 2048; \
  const float* b3_ = (LD) + 3072; \
  ALOAD(BUF[0][0], b0_, "0");    ALOAD(BUF[0][1], b0_, "16"); \
  ALOAD(BUF[1][0], b0_, "2048"); ALOAD(BUF[1][1], b0_, "2064"); \
  ALOAD(BUF[2][0], b1_, "0");    ALOAD(BUF[2][1], b1_, "16"); \
  ALOAD(BUF[3][0], b1_, "2048"); ALOAD(BUF[3][1], b1_, "2064"); \
  ALOAD(BUF[4][0], b2_, "0");    ALOAD(BUF[4][1], b2_, "16"); \
  ALOAD(BUF[5][0], b2_, "2048"); ALOAD(BUF[5][1], b2_, "2064"); \
  ALOAD(BUF[6][0], b3_, "0");    ALOAD(BUF[6][1], b3_, "16"); \
  ALOAD(BUF[7][0], b3_, "2048"); ALOAD(BUF[7][1], b3_, "2064"); } while (0)

// one scan step: p in (V0,V1); updates aw[8]; stores to SB at byte offsets O0/O1
#define STEP(V0, V1, SB, O0, O1) do { \
  float pp[8] = {(V0)[0], (V0)[1], (V0)[2], (V0)[3], (V1)[0], (V1)[1], (V1)[2], (V1)[3]}; \
  float cc[8]; \
  _Pragma("unroll") for (int i_ = 0; i_ < 8; ++i_) \
    cc[i_] = __builtin_fmaf(-aw[i_], pp[i_], aw[i_]); \
  float cL_ = __shfl_up(cc[7], 1); \
  float nw0_ = __builtin_fmaf(aw[0], pp[0], cL_ * m0f); \
  _Pragma("unroll") for (int i_ = 7; i_ >= 1; --i_) \
    aw[i_] = __builtin_fmaf(aw[i_], pp[i_], cc[i_ - 1]); \
  aw[0] = nw0_; \
  f32x4 s0_, s1_; \
  s0_[0] = aw[0]; s0_[1] = aw[1]; s0_[2] = aw[2]; s0_[3] = aw[3]; \
  s1_[0] = aw[4]; s1_[1] = aw[5]; s1_[2] = aw[6]; s1_[3] = aw[7]; \
  ASTORE16(SB, O0, s0_); ASTORE16(SB, O1, s1_); } while (0)

// compute+store 8 steps of BUF, outputs at OS (16 stores)
#define COMPUTE_CHUNK(BUF, OS) do { \
  float* o0_ = (OS); \
  float* o1_ = (OS) + 1024; \
  float* o2_ = (OS) + 2048; \
  float* o3_ = (OS) + 3072; \
  STEP(BUF[0][0], BUF[0][1], o0_, "0", "16"); \
  STEP(BUF[1][0], BUF[1][1], o0_, "2048", "2064"); \
  STEP(BUF[2][0], BUF[2][1], o1_, "0", "16"); \
  STEP(BUF[3][0], BUF[3][1], o1_, "2048", "2064"); \
  STEP(BUF[4][0], BUF[4][1], o2_, "0", "16"); \
  STEP(BUF[5][0], BUF[5][1], o2_, "2048", "2064"); \
  STEP(BUF[6][0], BUF[6][1], o3_, "0", "16"); \
  STEP(BUF[7][0], BUF[7][1], o3_, "2048", "2064"); } while (0)

__global__ __launch_bounds__(64, 1) void smma_scan_wave(const float* __restrict__ pT,
                                                        float* __restrict__ ame) {
  const int b = blockIdx.x, lane = threadIdx.x;
  const float* ld = pT + (size_t)b * KL * QL + lane * 8;
  float* os = ame + (size_t)b * KL * QL + lane * 8;
  const float m0f = (lane == 0) ? 0.f : 1.f;
  float aw[8];
  #pragma unroll
  for (int i = 0; i < 8; ++i) aw[i] = 0.f;
  if (lane == 0) aw[0] = 1.f;

  f32x4 A[8][2], B[8][2];
  LOAD_CHUNK(A, ld); ld += 8 * QL;      // chunk 0
  LOAD_CHUNK(B, ld); ld += 8 * QL;      // chunk 1

  // peeled first double-chunk (first wait sees only 2 chunks outstanding)
  WAITVM("16");
  COMPUTE_CHUNK(A, os); os += 8 * QL;
  LOAD_CHUNK(A, ld); ld += 8 * QL;      // chunk 2
  WAITVM("32");
  COMPUTE_CHUNK(B, os); os += 8 * QL;
  LOAD_CHUNK(B, ld); ld += 8 * QL;      // chunk 3

  for (int t = 1; t < 64; ++t) {
    WAITVM("32");
    COMPUTE_CHUNK(A, os); os += 8 * QL;
    LOAD_CHUNK(A, ld); ld += 8 * QL;    // over-reads <=16 rows past end: slack after PT
    WAITVM("32");
    COMPUTE_CHUNK(B, os); os += 8 * QL;
    LOAD_CHUNK(B, ld); ld += 8 * QL;
  }
}

// ---------------- transpose + convert: f32 [R][C] -> bf16 [C][R]  (round-7 proven) --------
__global__ __launch_bounds__(256) void transpose_cvt(
    const float* __restrict__ src, u16* __restrict__ dst, int R, int C) {
  __shared__ float tile[64][65];
  src += (size_t)blockIdx.z * R * C;
  dst += (size_t)blockIdx.z * R * C;
  const int r0 = blockIdx.x * 64, c0 = blockIdx.y * 64;
  {
    const int rr = threadIdx.x >> 4, cc = (threadIdx.x & 15) * 4;
    #pragma unroll
    for (int p = 0; p < 4; ++p) {
      float4 v = *(const float4*)&src[(size_t)(r0 + rr + p * 16) * C + c0 + cc];
      tile[rr + p * 16][cc] = v.x; tile[rr + p * 16][cc + 1] = v.y;
      tile[rr + p * 16][cc + 2] = v.z; tile[rr + p * 16][cc + 3] = v.w;
    }
  }
  __syncthreads();
  {
    const int oc = threadIdx.x >> 2, r8 = (threadIdx.x & 3) * 16;
    #pragma unroll
    for (int p = 0; p < 2; ++p) {
      union { u16 h[8]; uint4 u; } o;
      #pragma unroll
      for (int j = 0; j < 8; ++j) o.h[j] = f2b(tile[r8 + p * 8 + j][oc]);
      *(uint4*)&dst[(size_t)(c0 + oc) * R + r0 + r8 + p * 8] = o.u;
    }
  }
}

// ---------------- batched bf16 transpose: dst[c][r] = src[r][c] ----------------
__global__ __launch_bounds__(256) void transpose_bf16(
    const u16* __restrict__ src, u16* __restrict__ dst, int R, int C, long sz)
{
  __shared__ __align__(16) u16 tile[64][72];
  src += (size_t)blockIdx.z * sz;
  dst += (size_t)blockIdx.z * sz;
  const int r0 = blockIdx.x * 64, c0 = blockIdx.y * 64;
  {
    const int rr = threadIdx.x >> 3, c8 = (threadIdx.x & 7) * 8;
    #pragma unroll
    for (int p = 0; p < 2; ++p)
      *(uint4*)&tile[rr + p * 32][c8] =
          *(const uint4*)&src[(size_t)(r0 + rr + p * 32) * C + c0 + c8];
  }
  __syncthreads();
  {
    const int cc = threadIdx.x & 31, r8 = (threadIdx.x >> 5) * 8;
    #pragma unroll
    for (int p = 0; p < 2; ++p) {
      union { u16 h[8]; uint4 v; } o;
      #pragma unroll
      for (int j = 0; j < 8; ++j) o.h[j] = tile[r8 + j][cc + p * 32];
      *(uint4*)&dst[(size_t)(c0 + cc + p * 32) * R + r0 + r8] = o.v;
    }
  }
}

// ---------------- universal NT MFMA GEMM ----------------
template <bool OUT_BF16, bool BIAS>
__global__ __launch_bounds__(256) void gemm_nt(
    const u16* __restrict__ Aw, const u16* __restrict__ Bw,
    void* __restrict__ Cptr, const float* __restrict__ bias,
    int lda, int ldb, int ldc, int K, float alpha, int zdiv,
    long sA1, long sA0, long sB1, long sB0, long sC1, long sC0)
{
  __shared__ __align__(16) u16 As[128][72];
  __shared__ __align__(16) u16 Bs[128][72];
  const int tid = threadIdx.x;
  const int z = blockIdx.z;
  const int z1 = z / zdiv, z0 = z % zdiv;
  const int m0 = blockIdx.x * 128, n0 = blockIdx.y * 128;
  const u16* Ab = Aw + z1 * sA1 + z0 * sA0;
  const u16* Bz = Bw + z1 * sB1 + z0 * sB0;

  f32x4 acc[4][4];
  const f32x4 zero4 = {0.f, 0.f, 0.f, 0.f};
  #pragma unroll
  for (int m = 0; m < 4; ++m)
    #pragma unroll
    for (int n = 0; n < 4; ++n) acc[m][n] = zero4;

  const int rs = tid >> 3;
  const int k8 = (tid & 7) * 8;
  const int wv_ = tid >> 6, lane = tid & 63;
  const int wr = (wv_ >> 1) * 64, wc = (wv_ & 1) * 64;
  const int fr = lane & 15, fk = (lane >> 4) * 8;

  for (int k0 = 0; k0 < K; k0 += 64) {
    #pragma unroll
    for (int p = 0; p < 4; ++p)
      *(uint4*)&As[rs + p * 32][k8] =
          *(const uint4*)&Ab[(size_t)(m0 + rs + p * 32) * lda + k0 + k8];
    #pragma unroll
    for (int p = 0; p < 4; ++p)
      *(uint4*)&Bs[rs + p * 32][k8] =
          *(const uint4*)&Bz[(size_t)(n0 + rs + p * 32) * ldb + k0 + k8];
    __syncthreads();
    #pragma unroll
    for (int ks = 0; ks < 2; ++ks) {
      bf16x8 av[4], bv_[4];
      #pragma unroll
      for (int m = 0; m < 4; ++m)
        av[m] = *(const bf16x8*)&As[wr + m * 16 + fr][ks * 32 + fk];
      #pragma unroll
      for (int n = 0; n < 4; ++n)
        bv_[n] = *(const bf16x8*)&Bs[wc + n * 16 + fr][ks * 32 + fk];
      #pragma unroll
      for (int m = 0; m < 4; ++m)
        #pragma unroll
        for (int n = 0; n < 4; ++n)
          acc[m][n] = __builtin_amdgcn_mfma_f32_16x16x32_bf16(av[m], bv_[n], acc[m][n], 0, 0, 0);
    }
    __syncthreads();
  }

  const int crow = (lane >> 4) * 4;
  const long cbase = z1 * sC1 + z0 * sC0;
  #pragma unroll
  for (int m = 0; m < 4; ++m) {
    #pragma unroll
    for (int n = 0; n < 4; ++n) {
      const int gm = m0 + wr + m * 16 + crow;
      const int gn = n0 + wc + n * 16 + fr;
      float bval = 0.f;
      if constexpr (BIAS) bval = bias[gn];
      #pragma unroll
      for (int j = 0; j < 4; ++j) {
        float vv = acc[m][n][j] * alpha + bval;
        if constexpr (OUT_BF16)
          ((u16*)Cptr)[cbase + (size_t)(gm + j) * ldc + gn] = f2b(vv);
        else
          ((float*)Cptr)[cbase + (size_t)(gm + j) * ldc + gn] = vv;
      }
    }
  }
}

extern "C" void kernel_launch(void* const* d_in, const int* in_sizes, int n_in,
                              void* d_out, int out_size, void* d_ws, size_t ws_size,
                              hipStream_t stream) {
  const float* q      = (const float*)d_in[0];
  const float* k      = (const float*)d_in[1];
  const float* v      = (const float*)d_in[2];
  const int*   mel    = (const int*)d_in[3];
  const float* w_qs   = (const float*)d_in[4];
  const float* b_qs   = (const float*)d_in[5];
  const float* w_ks   = (const float*)d_in[6];
  const float* b_ks   = (const float*)d_in[7];
  const float* w_vs   = (const float*)d_in[8];
  const float* b_vs   = (const float*)d_in[9];
  const float* w_last = (const float*)d_in[10];
  const float* b_last = (const float*)d_in[11];

  char* ws = (char*)d_ws;
  float* out = (float*)d_out;

  u16* W2Q = (u16*)(ws + B_W2Q);
  u16* W2K = (u16*)(ws + B_W2K);
  u16* W2V = (u16*)(ws + B_W2V);
  u16* WLB = (u16*)(ws + B_WLB);
  u16* QH  = (u16*)(ws + B_QH);
  u16* KH  = (u16*)(ws + B_KH);
  u16* VH  = (u16*)(ws + B_VH);
  u16* E   = (u16*)(ws + B_E);
  float* AME = (float*)(ws + B_AME);
  u16* AMT = (u16*)(ws + B_AMT);
  float* MS = (float*)(ws + B_MS);
  float* CPART = (float*)(ws + B_CPART);
  float* FRR = (float*)(ws + B_FRR);
  int* HIDX = (int*)(ws + B_HIDX);
  float* PT = (float*)(ws + B_PT);
  u16* VHT = (u16*)(ws + B_VHT);
  u16* CVP = (u16*)(ws + B_CVP);

  // 1. weight repacks (swizzled)
  repack_all<<<dim3(2496, 1, 4), 256, 0, stream>>>(w_qs, w_ks, w_vs, w_last,
                                                   W2Q, W2K, W2V, WLB);

  // 2. grouped convs (round-8 proven ic-split form)
  conv_mfma<<<dim3(128, 1, 9), 256, 0, stream>>>(q, k, v, W2Q, W2K, W2V,
                                                 b_qs, b_ks, b_vs, QH, KH, VH);

  // 3. e (bf16) + fused row-max
  qk_flash<<<dim3(4, 1, 48), 256, 0, stream>>>(QH, KH, E, MS);

  // 4. softmax denominators + colmax partials (spill-free, vectorized)
  colsum_colmax<<<dim3(48, 8), 512, 0, stream>>>(E, MS, CPART);

  // 5. fr + head select
  head_fr<<<NH * NB, 256, 0, stream>>>(CPART, FRR);
  select_head<<<1, 64, 0, stream>>>(FRR, mel, HIDX, out + OUT_FR);

  // 6. gather alpha_fc -> d_out, sigmoid -> pT [b][k][q]
  gather_fused<<<dim3(KL / 32, QL / 32, NB), dim3(32, 8), 0, stream>>>(
      E, MS, HIDX, out + OUT_ALPHA, PT);

  // 7. register scan -> AME f32 [b][k][q] (coalesced; round-7 proven form)
  smma_scan_wave<<<NB, 64, 0, stream>>>(PT, AME);

  // 8. transposes: AME f32 -> AMT bf16 [b][q][k]; VH -> VHT [b][d][k]
  transpose_cvt<<<dim3(16, 8, NB), 256, 0, stream>>>(AME, AMT, KL, QL);
  transpose_bf16<<<dim3(16, 6, NB), 256, 0, stream>>>(VH, VHT, KL, DM, 393216);

  // 9. cv_pre[b][q][d] = sum_k amT[q][k] * vhT[d][k]
  gemm_nt<true, false><<<dim3(4, 3, NB), 256, 0, stream>>>(
      AMT, VHT, CVP, nullptr, KL, KL, DM, KL, 1.f, 1,
      524288L, 0, 393216L, 0, 196608L, 0);

  // 10. out = cv_pre @ w_last^T + b_last
  gemm_nt<false, true><<<dim3(64, 3, 1), 256, 0, stream>>>(
      CVP, WLB, out + OUT_CV, b_last, DM, DM, DM, DM, 1.f, 1,
      0, 0, 0, 0, 0, 0);
}

// Round 16
// 253.992 us; speedup vs baseline: 1.2304x; 1.0060x over previous
//
#include <hip/hip_runtime.h>

#define NB 16
#define QL 512
#define KL 1024
#define DM 384
#define NH 3
#define DK 128

typedef unsigned short u16;
typedef __attribute__((ext_vector_type(8))) short bf16x8;
typedef __attribute__((ext_vector_type(4))) float f32x4;
typedef __attribute__((ext_vector_type(4))) unsigned int u32x4;

// ---------------- workspace byte offsets ----------------
static const size_t B_W2Q = 0;            // bf16 [384][1664] (granule-swizzled)
static const size_t B_W2K = 1277952;
static const size_t B_W2V = 2555904;
static const size_t B_WLB = 3833856;      // bf16 [384][384]
static const size_t B_QH  = 4128768;      // bf16 [16*512][384]
static const size_t B_KH  = 10420224;     // bf16 [16*1024][384]
static const size_t B_VH  = 23003136;     // bf16 [16*1024][384]
static const size_t B_E   = 67043328;     // bf16 [48][512][1024]
static const size_t B_AME = 67043328;     // f32 [16][1024][512] scan out (aliases dead E-low)
static const size_t B_AMT = 100597760;    // bf16 [16][512][1024] (aliases dead E-high)
static const size_t B_MS  = 117374976;    // f32 [48*512][2] {rowmax, inv}
static const size_t B_CPART = 117571584;  // f32 [48][8][1024]
static const size_t B_FRR = 119144448;    // f32 [48]
static const size_t B_HIDX = 119144704;   // int [16]
static const size_t B_PT  = 119144960;    // f32 [16][1024][512] (+64KB slack after)
static const size_t B_VHT = 152764928;    // bf16 [16][384][1024]
static const size_t B_CVP = 165347840;    // bf16 [16][512][384]

// d_out offsets (floats)
static const size_t OUT_CV    = 0;
static const size_t OUT_ALPHA = 3145728;
static const size_t OUT_FR    = 11534336;

__device__ __forceinline__ u16 f2b(float x) {
  union { float f; unsigned u; } q; q.f = x;
  unsigned r = q.u + 0x7fffu + ((q.u >> 16) & 1u);
  return (u16)(r >> 16);
}
__device__ __forceinline__ float b2f(u16 h) {
  union { unsigned u; float f; } q; q.u = ((unsigned)h) << 16;
  return q.f;
}

typedef __attribute__((address_space(3))) void lds_void;
typedef __attribute__((address_space(1))) const void g_void;
__device__ __forceinline__ void gload_lds16(const void* g, void* l) {
  __builtin_amdgcn_global_load_lds((g_void*)g, (lds_void*)l, 16, 0, 0);
}

// ---------------- weight repacks ----------------
__global__ __launch_bounds__(256) void repack_all(
    const float* __restrict__ wq, const float* __restrict__ wk,
    const float* __restrict__ wv, const float* __restrict__ wl,
    u16* __restrict__ dq, u16* __restrict__ dk, u16* __restrict__ dv,
    u16* __restrict__ dl) {
  const int z = blockIdx.z;
  const int tid = blockIdx.x * 256 + threadIdx.x;
  if (z < 3) {
    if (tid >= 384 * 1664) return;
    const float* src = (z == 0) ? wq : (z == 1) ? wk : wv;
    u16* dst = (z == 0) ? dq : (z == 1) ? dk : dv;
    const int oc = tid / 1664, k = tid % 1664;     // logical k
    const int t = k >> 7, ic = k & 127;
    const int g = (k >> 3) & 7, e = k & 7;
    const int pcol = (k & ~63) + (((g ^ (oc & 7))) << 3) + e;
    dst[(size_t)oc * 1664 + pcol] = f2b(src[(size_t)oc * 1664 + ic * 13 + t]);
  } else {
    if (tid < 384 * 384) dl[tid] = f2b(wl[tid]);
  }
}

// ---------------- grouped conv1d: 2-pass ic-split (round-8 proven form) ----------------
// z/3 selects tensor (0=q L=512, 1=k, 2=v L=1024); z%3 = group
__global__ __launch_bounds__(256, 4) void conv_mfma(
    const float* __restrict__ xq, const float* __restrict__ xk, const float* __restrict__ xv,
    const u16* __restrict__ wq, const u16* __restrict__ wk, const u16* __restrict__ wv,
    const float* __restrict__ bq, const float* __restrict__ bk, const float* __restrict__ bv,
    u16* __restrict__ oq, u16* __restrict__ ok, u16* __restrict__ ov)
{
  __shared__ __align__(16) u16 xw[140][72];
  __shared__ __align__(16) u16 Bs[128 * 64];    // unpadded, granule-swizzled content
  const int z = blockIdx.z;
  const int which = z / 3, g = z % 3;
  const float* X; const u16* W; const float* bias; u16* out; int Lmask;
  if (which == 0)      { X = xq; W = wq; bias = bq; out = oq; Lmask = 511; }
  else if (which == 1) { X = xk; W = wk; bias = bk; out = ok; Lmask = 1023; }
  else                 { X = xv; W = wv; bias = bv; out = ov; Lmask = 1023; }
  const int m0 = blockIdx.x * 128;
  if (m0 >= NB * (Lmask + 1)) return;
  X += g * DK; W += (size_t)g * DK * 1664; bias += g * DK; out += g * DK;

  const int tid = threadIdx.x;
  const int l0 = m0 & Lmask, bbase = m0 & ~Lmask;

  const int wv_ = tid >> 6, lane = tid & 63;
  const int wr = (wv_ >> 1) * 64, wc = (wv_ & 1) * 64;
  const int fr = lane & 15, fk8 = (lane >> 4);
  const int srow = lane >> 3, sg = lane & 7;

  f32x4 acc[4][4];
  const f32x4 zero4 = {0.f, 0.f, 0.f, 0.f};
  #pragma unroll
  for (int m = 0; m < 4; ++m)
    #pragma unroll
    for (int n = 0; n < 4; ++n) acc[m][n] = zero4;

  for (int h = 0; h < 2; ++h) {
    __syncthreads();   // all reads of xw (prev pass) done
    // stage this pass's 140-row x 64-ic window, f32 -> bf16 in flight
    for (int i = tid; i < 140 * 16; i += 256) {
      const int r = i >> 4, c4 = (i & 15) * 4;
      const int l = l0 - 6 + r;
      float4 v = make_float4(0.f, 0.f, 0.f, 0.f);
      if ((unsigned)l <= (unsigned)Lmask)
        v = *(const float4*)&X[(size_t)(bbase + l) * DM + h * 64 + c4];
      union { u16 u[4]; uint2 d; } o;
      o.u[0] = f2b(v.x); o.u[1] = f2b(v.y); o.u[2] = f2b(v.z); o.u[3] = f2b(v.w);
      *(uint2*)&xw[r][c4] = o.d;
    }
    for (int t = 0; t < 13; ++t) {
      const int k0 = t * 128 + h * 64;
      __syncthreads();   // xw ready (t==0) / prior Bs reads done
      #pragma unroll
      for (int i = 0; i < 4; ++i) {
        const int ii = wv_ + i * 4;
        gload_lds16(&W[(size_t)(8 * ii + srow) * 1664 + k0 + sg * 8],
                    (char*)Bs + ii * 1024);
      }
      __syncthreads();   // compiler drains vmcnt before barrier
      #pragma unroll
      for (int ks = 0; ks < 2; ++ks) {
        bf16x8 av[4], bv_[4];
        #pragma unroll
        for (int m = 0; m < 4; ++m)
          av[m] = *(const bf16x8*)&xw[t + wr + m * 16 + fr][ks * 32 + fk8 * 8];
        #pragma unroll
        for (int n = 0; n < 4; ++n) {
          const int r = wc + n * 16 + fr;
          const int pg = (ks * 4 + fk8) ^ (fr & 7);
          bv_[n] = *(const bf16x8*)&Bs[r * 64 + pg * 8];
        }
        #pragma unroll
        for (int m = 0; m < 4; ++m)
          #pragma unroll
          for (int n = 0; n < 4; ++n)
            acc[m][n] = __builtin_amdgcn_mfma_f32_16x16x32_bf16(av[m], bv_[n], acc[m][n], 0, 0, 0);
      }
    }
  }

  const int crow = (lane >> 4) * 4;
  #pragma unroll
  for (int m = 0; m < 4; ++m) {
    #pragma unroll
    for (int n = 0; n < 4; ++n) {
      const int gm = m0 + wr + m * 16 + crow;
      const int gn = wc + n * 16 + fr;
      const float bval = bias[gn];
      #pragma unroll
      for (int j = 0; j < 4; ++j)
        out[(size_t)(gm + j) * DM + gn] = f2b(acc[m][n][j] + bval);
    }
  }
}

// ---------------- qk: E[z][q][k] = qh.kh/sqrt(128) (bf16 out) + fused row-max ----------------
__global__ __launch_bounds__(256) void qk_flash(
    const u16* __restrict__ QH, const u16* __restrict__ KH,
    u16* __restrict__ E, float* __restrict__ MS)
{
  __shared__ __align__(16) u16 As[128][136];
  __shared__ __align__(16) u16 Bs[128][136];
  __shared__ float rmx[2][128];
  const int tid = threadIdx.x;
  const int z = blockIdx.z, h = z >> 4, b = z & 15;
  const int m0 = blockIdx.x * 128;
  const u16* Ag = QH + ((size_t)b * QL + m0) * DM + h * DK;
  const u16* Bg = KH + (size_t)b * KL * DM + h * DK;
  u16* Ez = E + (size_t)z * QL * KL;

  for (int i = tid; i < 128 * 16; i += 256) {
    const int r = i >> 4, s = i & 15;
    *(uint4*)&As[r][s * 8] = *(const uint4*)&Ag[(size_t)r * DM + s * 8];
  }

  const int wv_ = tid >> 6, lane = tid & 63;
  const int wr = (wv_ >> 1) * 64, wc = (wv_ & 1) * 64;
  const int fr = lane & 15, fk = (lane >> 4) * 8;
  const int crow = (lane >> 4) * 4;
  const float sc = 0.08838834764831845f;

  float mx[4][4];
  #pragma unroll
  for (int m = 0; m < 4; ++m)
    #pragma unroll
    for (int j = 0; j < 4; ++j) mx[m][j] = -1e30f;

  for (int nt = 0; nt < 8; ++nt) {
    if (nt) __syncthreads();
    for (int i = tid; i < 128 * 16; i += 256) {
      const int r = i >> 4, s = i & 15;
      *(uint4*)&Bs[r][s * 8] = *(const uint4*)&Bg[(size_t)(nt * 128 + r) * DM + s * 8];
    }
    __syncthreads();

    f32x4 acc[4][4];
    const f32x4 zero4 = {0.f, 0.f, 0.f, 0.f};
    #pragma unroll
    for (int m = 0; m < 4; ++m)
      #pragma unroll
      for (int n = 0; n < 4; ++n) acc[m][n] = zero4;
    #pragma unroll
    for (int ks = 0; ks < 4; ++ks) {
      bf16x8 av[4], bv_[4];
      #pragma unroll
      for (int m = 0; m < 4; ++m)
        av[m] = *(const bf16x8*)&As[wr + m * 16 + fr][ks * 32 + fk];
      #pragma unroll
      for (int n = 0; n < 4; ++n)
        bv_[n] = *(const bf16x8*)&Bs[wc + n * 16 + fr][ks * 32 + fk];
      #pragma unroll
      for (int m = 0; m < 4; ++m)
        #pragma unroll
        for (int n = 0; n < 4; ++n)
          acc[m][n] = __builtin_amdgcn_mfma_f32_16x16x32_bf16(av[m], bv_[n], acc[m][n], 0, 0, 0);
    }
    #pragma unroll
    for (int m = 0; m < 4; ++m) {
      #pragma unroll
      for (int n = 0; n < 4; ++n) {
        const int gm = m0 + wr + m * 16 + crow;
        const int gn = nt * 128 + wc + n * 16 + fr;
        #pragma unroll
        for (int j = 0; j < 4; ++j) {
          const float vv = acc[m][n][j] * sc;
          mx[m][j] = fmaxf(mx[m][j], vv);
          Ez[(size_t)(gm + j) * KL + gn] = f2b(vv);
        }
      }
    }
  }

  #pragma unroll
  for (int m = 0; m < 4; ++m)
    #pragma unroll
    for (int j = 0; j < 4; ++j) {
      #pragma unroll
      for (int off = 1; off < 16; off <<= 1)
        mx[m][j] = fmaxf(mx[m][j], __shfl_xor(mx[m][j], off));
    }
  if ((lane & 15) == 0) {
    #pragma unroll
    for (int m = 0; m < 4; ++m)
      #pragma unroll
      for (int j = 0; j < 4; ++j)
        rmx[wv_ & 1][wr + m * 16 + crow + j] = mx[m][j];
  }
  __syncthreads();
  if (tid < 128)
    MS[2 * ((size_t)z * QL + m0 + tid)] = fmaxf(rmx[0][tid], rmx[1][tid]);
}

// ---------------- per (z,qc): softmax denominators + column-max partials -------------------
// (round-14 proven spill-free form)
__global__ __launch_bounds__(512) void colsum_colmax(
    const u16* __restrict__ E, float* __restrict__ MS, float* __restrict__ cpart)
{
  __shared__ float cm_s[8][1024];
  const int z = blockIdx.x, qc = blockIdx.y;
  const int tid = threadIdx.x;
  const int w = tid >> 6, lane = tid & 63;
  const u16* base = E + ((size_t)z * QL + qc * 64) * KL;
  const size_t msrow = (size_t)z * QL + qc * 64;

  float cm[16];
  #pragma unroll
  for (int j = 0; j < 16; ++j) cm[j] = 0.f;

  for (int r8 = 0; r8 < 8; ++r8) {
    const int r = w + 8 * r8;
    const float m = MS[2 * (msrow + r)];
    union { u16 h[8]; uint4 v; } a, b;
    a.v = *(const uint4*)&base[(size_t)r * KL + lane * 8];
    b.v = *(const uint4*)&base[(size_t)r * KL + 512 + lane * 8];
    float ex[16];
    #pragma unroll
    for (int j = 0; j < 8; ++j) {
      ex[j] = expf(b2f(a.h[j]) - m);
      ex[8 + j] = expf(b2f(b.h[j]) - m);
    }
    float s = 0.f;
    #pragma unroll
    for (int j = 0; j < 16; ++j) s += ex[j];
    #pragma unroll
    for (int off = 32; off; off >>= 1) s += __shfl_xor(s, off);
    const float inv = 1.f / s;
    if (lane == 0) MS[2 * (msrow + r) + 1] = inv;
    #pragma unroll
    for (int j = 0; j < 16; ++j) cm[j] = fmaxf(cm[j], ex[j] * inv);
  }

  #pragma unroll
  for (int j = 0; j < 8; ++j) {
    cm_s[w][lane * 8 + j] = cm[j];
    cm_s[w][512 + lane * 8 + j] = cm[8 + j];
  }
  __syncthreads();
  for (int c = tid; c < 1024; c += 512) {
    float m = 0.f;
    #pragma unroll
    for (int w2 = 0; w2 < 8; ++w2) m = fmaxf(m, cm_s[w2][c]);
    cpart[((size_t)z * 8 + qc) * KL + c] = m;
  }
}

// ---------------- fr per (h,b): sum_k max over 8 q-chunks ----------------
__global__ __launch_bounds__(256) void head_fr(const float* __restrict__ cpart,
                                               float* __restrict__ frr) {
  const int z = blockIdx.x, tid = threadIdx.x;
  float s = 0.f;
  for (int k = tid; k < KL; k += 256) {
    float m = 0.f;
    #pragma unroll
    for (int c = 0; c < 8; ++c) m = fmaxf(m, cpart[((size_t)z * 8 + c) * KL + k]);
    s += m;
  }
  #pragma unroll
  for (int off = 32; off; off >>= 1) s += __shfl_xor(s, off);
  __shared__ float red[4];
  if ((tid & 63) == 0) red[tid >> 6] = s;
  __syncthreads();
  if (tid == 0) frr[z] = red[0] + red[1] + red[2] + red[3];
}

// ---------------- head select ----------------
__global__ void select_head(const float* __restrict__ frr, const int* __restrict__ mel,
                            int* __restrict__ hidx, float* __restrict__ fr_out) {
  __shared__ float bf[16];
  const int b = threadIdx.x;
  if (b < 16) {
    float best = -1e30f; int bh = 0;
    for (int h = 0; h < NH; ++h) {
      float fr = frr[h * 16 + b] / (float)mel[b];
      if (fr > best) { best = fr; bh = h; }
    }
    hidx[b] = bh;
    bf[b] = best;
  }
  __syncthreads();
  if (threadIdx.x == 0) {
    float s = 0.f;
    for (int i = 0; i < 16; ++i) s += bf[i];
    *fr_out = s / 16.f;
  }
}

// ---------------- gather selected head: alpha -> d_out; sigmoid(alpha)^T -> pT ----------------
__global__ __launch_bounds__(256) void gather_fused(
    const u16* __restrict__ E, const float* __restrict__ ms,
    const int* __restrict__ hidx, float* __restrict__ afc, float* __restrict__ pT)
{
  __shared__ float tile[32][33];
  const int b = blockIdx.z, k0 = blockIdx.x * 32, q0 = blockIdx.y * 32;
  const int hb = hidx[b];
  const u16* src = E + (size_t)(hb * 16 + b) * QL * KL;
  const float* msb = ms + 2 * ((size_t)(hb * 16 + b) * QL + q0);
  const int tx = threadIdx.x, ty = threadIdx.y;
  #pragma unroll
  for (int yy = 0; yy < 4; ++yy) {
    int r = ty + 8 * yy;
    float m = msb[2 * r], inv = msb[2 * r + 1];
    float v = expf(b2f(src[(size_t)(q0 + r) * KL + k0 + tx]) - m) * inv;
    afc[((size_t)b * QL + q0 + r) * KL + k0 + tx] = v;
    tile[r][tx] = v;
  }
  __syncthreads();
  #pragma unroll
  for (int yy = 0; yy < 4; ++yy) {
    int c = ty + 8 * yy;
    float v = tile[tx][c];
    pT[((size_t)b * KL + k0 + c) * QL + q0 + tx] = 1.f / (1.f + expf(-v));
  }
}

// ================= scan: asm prefetch + counted vmcnt, f32 coalesced [k][q] out ============
// (round-7 proven form, verbatim)
#define ALOAD(dst, base, OFF) \
  asm volatile("global_load_dwordx4 %0, %1, off offset:" OFF : "=v"(dst) : "v"(base))
#define ASTORE16(base, OFF, val) \
  asm volatile("global_store_dwordx4 %0, %1, off offset:" OFF :: "v"(base), "v"(val) : "memory")
#define WAITVM(N) do { \
  asm volatile("s_waitcnt vmcnt(" N ")" ::: "memory"); \
  __builtin_amdgcn_sched_barrier(0); } while (0)

// load 8 rows (16 dwordx4) starting at LD into BUF[8][2]
#define LOAD_CHUNK(BUF, LD) do { \
  const float* b0_ = (LD); \
  const float* b1_ = (LD) + 1024; \
  const float* b2_ = (LD) + 2048; \
  const float* b3_ = (LD) + 3072; \
  ALOAD(BUF[0][0], b0_, "0");    ALOAD(BUF[0][1], b0_, "16"); \
  ALOAD(BUF[1][0], b0_, "2048"); ALOAD(BUF[1][1], b0_, "2064"); \
  ALOAD(BUF[2][0], b1_, "0");    ALOAD(BUF[2][1], b1_, "16"); \
  ALOAD(BUF[3][0], b1_, "2048"); ALOAD(BUF[3][1], b1_, "2064"); \
  ALOAD(BUF[4][0], b2_, "0");    ALOAD(BUF[4][1], b2_, "16"); \
  ALOAD(BUF[5][0], b2_, "2048"); ALOAD(BUF[5][1], b2_, "2064"); \
  ALOAD(BUF[6][0], b3_, "0");    ALOAD(BUF[6][1], b3_, "16"); \
  ALOAD(BUF[7][0], b3_, "2048"); ALOAD(BUF[7][1], b3_, "2064"); } while (0)

// one scan step: p in (V0,V1); updates aw[8]; stores to SB at byte offsets O0/O1
#define STEP(V0, V1, SB, O0, O1) do { \
  float pp[8] = {(V0)[0], (V0)[1], (V0)[2], (V0)[3], (V1)[0], (V1)[1], (V1)[2], (V1)[3]}; \
  float cc[8]; \
  _Pragma("unroll") for (int i_ = 0; i_ < 8; ++i_) \
    cc[i_] = __builtin_fmaf(-aw[i_], pp[i_], aw[i_]); \
  float cL_ = __shfl_up(cc[7], 1); \
  float nw0_ = __builtin_fmaf(aw[0], pp[0], cL_ * m0f); \
  _Pragma("unroll") for (int i_ = 7; i_ >= 1; --i_) \
    aw[i_] = __builtin_fmaf(aw[i_], pp[i_], cc[i_ - 1]); \
  aw[0] = nw0_; \
  f32x4 s0_, s1_; \
  s0_[0] = aw[0]; s0_[1] = aw[1]; s0_[2] = aw[2]; s0_[3] = aw[3]; \
  s1_[0] = aw[4]; s1_[1] = aw[5]; s1_[2] = aw[6]; s1_[3] = aw[7]; \
  ASTORE16(SB, O0, s0_); ASTORE16(SB, O1, s1_); } while (0)

// compute+store 8 steps of BUF, outputs at OS (16 stores)
#define COMPUTE_CHUNK(BUF, OS) do { \
  float* o0_ = (OS); \
  float* o1_ = (OS) + 1024; \
  float* o2_ = (OS) + 2048; \
  float* o3_ = (OS) + 3072; \
  STEP(BUF[0][0], BUF[0][1], o0_, "0", "16"); \
  STEP(BUF[1][0], BUF[1][1], o0_, "2048", "2064"); \
  STEP(BUF[2][0], BUF[2][1], o1_, "0", "16"); \
  STEP(BUF[3][0], BUF[3][1], o1_, "2048", "2064"); \
  STEP(BUF[4][0], BUF[4][1], o2_, "0", "16"); \
  STEP(BUF[5][0], BUF[5][1], o2_, "2048", "2064"); \
  STEP(BUF[6][0], BUF[6][1], o3_, "0", "16"); \
  STEP(BUF[7][0], BUF[7][1], o3_, "2048", "2064"); } while (0)

__global__ __launch_bounds__(64, 1) void smma_scan_wave(const float* __restrict__ pT,
                                                        float* __restrict__ ame) {
  const int b = blockIdx.x, lane = threadIdx.x;
  const float* ld = pT + (size_t)b * KL * QL + lane * 8;
  float* os = ame + (size_t)b * KL * QL + lane * 8;
  const float m0f = (lane == 0) ? 0.f : 1.f;
  float aw[8];
  #pragma unroll
  for (int i = 0; i < 8; ++i) aw[i] = 0.f;
  if (lane == 0) aw[0] = 1.f;

  f32x4 A[8][2], B[8][2];
  LOAD_CHUNK(A, ld); ld += 8 * QL;      // chunk 0
  LOAD_CHUNK(B, ld); ld += 8 * QL;      // chunk 1

  // peeled first double-chunk (first wait sees only 2 chunks outstanding)
  WAITVM("16");
  COMPUTE_CHUNK(A, os); os += 8 * QL;
  LOAD_CHUNK(A, ld); ld += 8 * QL;      // chunk 2
  WAITVM("32");
  COMPUTE_CHUNK(B, os); os += 8 * QL;
  LOAD_CHUNK(B, ld); ld += 8 * QL;      // chunk 3

  for (int t = 1; t < 64; ++t) {
    WAITVM("32");
    COMPUTE_CHUNK(A, os); os += 8 * QL;
    LOAD_CHUNK(A, ld); ld += 8 * QL;    // over-reads <=16 rows past end: slack after PT
    WAITVM("32");
    COMPUTE_CHUNK(B, os); os += 8 * QL;
    LOAD_CHUNK(B, ld); ld += 8 * QL;
  }
}

// ---------------- transpose + convert: f32 [R][C] -> bf16 [C][R]  (round-7 proven) --------
__global__ __launch_bounds__(256) void transpose_cvt(
    const float* __restrict__ src, u16* __restrict__ dst, int R, int C) {
  __shared__ float tile[64][65];
  src += (size_t)blockIdx.z * R * C;
  dst += (size_t)blockIdx.z * R * C;
  const int r0 = blockIdx.x * 64, c0 = blockIdx.y * 64;
  {
    const int rr = threadIdx.x >> 4, cc = (threadIdx.x & 15) * 4;
    #pragma unroll
    for (int p = 0; p < 4; ++p) {
      float4 v = *(const float4*)&src[(size_t)(r0 + rr + p * 16) * C + c0 + cc];
      tile[rr + p * 16][cc] = v.x; tile[rr + p * 16][cc + 1] = v.y;
      tile[rr + p * 16][cc + 2] = v.z; tile[rr + p * 16][cc + 3] = v.w;
    }
  }
  __syncthreads();
  {
    const int oc = threadIdx.x >> 2, r8 = (threadIdx.x & 3) * 16;
    #pragma unroll
    for (int p = 0; p < 2; ++p) {
      union { u16 h[8]; uint4 u; } o;
      #pragma unroll
      for (int j = 0; j < 8; ++j) o.h[j] = f2b(tile[r8 + p * 8 + j][oc]);
      *(uint4*)&dst[(size_t)(c0 + oc) * R + r0 + r8 + p * 8] = o.u;
    }
  }
}

// ---------------- batched bf16 transpose: dst[c][r] = src[r][c] ----------------
__global__ __launch_bounds__(256) void transpose_bf16(
    const u16* __restrict__ src, u16* __restrict__ dst, int R, int C, long sz)
{
  __shared__ __align__(16) u16 tile[64][72];
  src += (size_t)blockIdx.z * sz;
  dst += (size_t)blockIdx.z * sz;
  const int r0 = blockIdx.x * 64, c0 = blockIdx.y * 64;
  {
    const int rr = threadIdx.x >> 3, c8 = (threadIdx.x & 7) * 8;
    #pragma unroll
    for (int p = 0; p < 2; ++p)
      *(uint4*)&tile[rr + p * 32][c8] =
          *(const uint4*)&src[(size_t)(r0 + rr + p * 32) * C + c0 + c8];
  }
  __syncthreads();
  {
    const int cc = threadIdx.x & 31, r8 = (threadIdx.x >> 5) * 8;
    #pragma unroll
    for (int p = 0; p < 2; ++p) {
      union { u16 h[8]; uint4 v; } o;
      #pragma unroll
      for (int j = 0; j < 8; ++j) o.h[j] = tile[r8 + j][cc + p * 32];
      *(uint4*)&dst[(size_t)(c0 + cc + p * 32) * R + r0 + r8] = o.v;
    }
  }
}

// ---------------- universal NT MFMA GEMM ----------------
template <bool OUT_BF16, bool BIAS>
__global__ __launch_bounds__(256) void gemm_nt(
    const u16* __restrict__ Aw, const u16* __restrict__ Bw,
    void* __restrict__ Cptr, const float* __restrict__ bias,
    int lda, int ldb, int ldc, int K, float alpha, int zdiv,
    long sA1, long sA0, long sB1, long sB0, long sC1, long sC0)
{
  __shared__ __align__(16) u16 As[128][72];
  __shared__ __align__(16) u16 Bs[128][72];
  const int tid = threadIdx.x;
  const int z = blockIdx.z;
  const int z1 = z / zdiv, z0 = z % zdiv;
  const int m0 = blockIdx.x * 128, n0 = blockIdx.y * 128;
  const u16* Ab = Aw + z1 * sA1 + z0 * sA0;
  const u16* Bz = Bw + z1 * sB1 + z0 * sB0;

  f32x4 acc[4][4];
  const f32x4 zero4 = {0.f, 0.f, 0.f, 0.f};
  #pragma unroll
  for (int m = 0; m < 4; ++m)
    #pragma unroll
    for (int n = 0; n < 4; ++n) acc[m][n] = zero4;

  const int rs = tid >> 3;
  const int k8 = (tid & 7) * 8;
  const int wv_ = tid >> 6, lane = tid & 63;
  const int wr = (wv_ >> 1) * 64, wc = (wv_ & 1) * 64;
  const int fr = lane & 15, fk = (lane >> 4) * 8;

  for (int k0 = 0; k0 < K; k0 += 64) {
    #pragma unroll
    for (int p = 0; p < 4; ++p)
      *(uint4*)&As[rs + p * 32][k8] =
          *(const uint4*)&Ab[(size_t)(m0 + rs + p * 32) * lda + k0 + k8];
    #pragma unroll
    for (int p = 0; p < 4; ++p)
      *(uint4*)&Bs[rs + p * 32][k8] =
          *(const uint4*)&Bz[(size_t)(n0 + rs + p * 32) * ldb + k0 + k8];
    __syncthreads();
    #pragma unroll
    for (int ks = 0; ks < 2; ++ks) {
      bf16x8 av[4], bv_[4];
      #pragma unroll
      for (int m = 0; m < 4; ++m)
        av[m] = *(const bf16x8*)&As[wr + m * 16 + fr][ks * 32 + fk];
      #pragma unroll
      for (int n = 0; n < 4; ++n)
        bv_[n] = *(const bf16x8*)&Bs[wc + n * 16 + fr][ks * 32 + fk];
      #pragma unroll
      for (int m = 0; m < 4; ++m)
        #pragma unroll
        for (int n = 0; n < 4; ++n)
          acc[m][n] = __builtin_amdgcn_mfma_f32_16x16x32_bf16(av[m], bv_[n], acc[m][n], 0, 0, 0);
    }
    __syncthreads();
  }

  const int crow = (lane >> 4) * 4;
  const long cbase = z1 * sC1 + z0 * sC0;
  #pragma unroll
  for (int m = 0; m < 4; ++m) {
    #pragma unroll
    for (int n = 0; n < 4; ++n) {
      const int gm = m0 + wr + m * 16 + crow;
      const int gn = n0 + wc + n * 16 + fr;
      float bval = 0.f;
      if constexpr (BIAS) bval = bias[gn];
      #pragma unroll
      for (int j = 0; j < 4; ++j) {
        float vv = acc[m][n][j] * alpha + bval;
        if constexpr (OUT_BF16)
          ((u16*)Cptr)[cbase + (size_t)(gm + j) * ldc + gn] = f2b(vv);
        else
          ((float*)Cptr)[cbase + (size_t)(gm + j) * ldc + gn] = vv;
      }
    }
  }
}

extern "C" void kernel_launch(void* const* d_in, const int* in_sizes, int n_in,
                              void* d_out, int out_size, void* d_ws, size_t ws_size,
                              hipStream_t stream) {
  const float* q      = (const float*)d_in[0];
  const float* k      = (const float*)d_in[1];
  const float* v      = (const float*)d_in[2];
  const int*   mel    = (const int*)d_in[3];
  const float* w_qs   = (const float*)d_in[4];
  const float* b_qs   = (const float*)d_in[5];
  const float* w_ks   = (const float*)d_in[6];
  const float* b_ks   = (const float*)d_in[7];
  const float* w_vs   = (const float*)d_in[8];
  const float* b_vs   = (const float*)d_in[9];
  const float* w_last = (const float*)d_in[10];
  const float* b_last = (const float*)d_in[11];

  char* ws = (char*)d_ws;
  float* out = (float*)d_out;

  u16* W2Q = (u16*)(ws + B_W2Q);
  u16* W2K = (u16*)(ws + B_W2K);
  u16* W2V = (u16*)(ws + B_W2V);
  u16* WLB = (u16*)(ws + B_WLB);
  u16* QH  = (u16*)(ws + B_QH);
  u16* KH  = (u16*)(ws + B_KH);
  u16* VH  = (u16*)(ws + B_VH);
  u16* E   = (u16*)(ws + B_E);
  float* AME = (float*)(ws + B_AME);
  u16* AMT = (u16*)(ws + B_AMT);
  float* MS = (float*)(ws + B_MS);
  float* CPART = (float*)(ws + B_CPART);
  float* FRR = (float*)(ws + B_FRR);
  int* HIDX = (int*)(ws + B_HIDX);
  float* PT = (float*)(ws + B_PT);
  u16* VHT = (u16*)(ws + B_VHT);
  u16* CVP = (u16*)(ws + B_CVP);

  // 1. weight repacks (swizzled)
  repack_all<<<dim3(2496, 1, 4), 256, 0, stream>>>(w_qs, w_ks, w_vs, w_last,
                                                   W2Q, W2K, W2V, WLB);

  // 2. grouped convs (round-8 proven ic-split form)
  conv_mfma<<<dim3(128, 1, 9), 256, 0, stream>>>(q, k, v, W2Q, W2K, W2V,
                                                 b_qs, b_ks, b_vs, QH, KH, VH);

  // 3. e (bf16) + fused row-max
  qk_flash<<<dim3(4, 1, 48), 256, 0, stream>>>(QH, KH, E, MS);

  // 4. softmax denominators + colmax partials (spill-free, vectorized)
  colsum_colmax<<<dim3(48, 8), 512, 0, stream>>>(E, MS, CPART);

  // 5. fr + head select
  head_fr<<<NH * NB, 256, 0, stream>>>(CPART, FRR);
  select_head<<<1, 64, 0, stream>>>(FRR, mel, HIDX, out + OUT_FR);

  // 6. gather alpha_fc -> d_out, sigmoid -> pT [b][k][q]
  gather_fused<<<dim3(KL / 32, QL / 32, NB), dim3(32, 8), 0, stream>>>(
      E, MS, HIDX, out + OUT_ALPHA, PT);

  // 7. register scan -> AME f32 [b][k][q] (coalesced; round-7 proven form)
  smma_scan_wave<<<NB, 64, 0, stream>>>(PT, AME);

  // 8. transposes: AME f32 -> AMT bf16 [b][q][k]; VH -> VHT [b][d][k]
  transpose_cvt<<<dim3(16, 8, NB), 256, 0, stream>>>(AME, AMT, KL, QL);
  transpose_bf16<<<dim3(16, 6, NB), 256, 0, stream>>>(VH, VHT, KL, DM, 393216);

  // 9. cv_pre[b][q][d] = sum_k amT[q][k] * vhT[d][k]
  gemm_nt<true, false><<<dim3(4, 3, NB), 256, 0, stream>>>(
      AMT, VHT, CVP, nullptr, KL, KL, DM, KL, 1.f, 1,
      524288L, 0, 393216L, 0, 196608L, 0);

  // 10. out = cv_pre @ w_last^T + b_last
  gemm_nt<false, true><<<dim3(64, 3, 1), 256, 0, stream>>>(
      CVP, WLB, out + OUT_CV, b_last, DM, DM, DM, DM, 1.f, 1,
      0, 0, 0, 0, 0, 0);
}